// Round 2
// baseline (578.956 us; speedup 1.0000x reference)
//
#include <hip/hip_runtime.h>
#include <hip/hip_bf16.h>

typedef _Float16 f16;
typedef __attribute__((ext_vector_type(8))) _Float16 f16x8;
typedef __attribute__((ext_vector_type(4))) float f32x4;

#define DIM 1024
#define SEQ 4096
#define KRNK 256
#define NH 16
#define HD 64
#define NB 4
#define ROWS (NB*SEQ)   // 16384

typedef const void __attribute__((address_space(1))) as1cv;
typedef void __attribute__((address_space(3))) as3v;

static __device__ __forceinline__ void glds16(const void* g, void* l) {
  __builtin_amdgcn_global_load_lds((as1cv*)g, (as3v*)l, 16, 0, 0);
}

// ---------------- W prep: transpose fp32 -> fp16 (MODE 0: scaled x256 hi/lo pair; 1: single) ----
template<int MODE>
__global__ __launch_bounds__(256) void k_prep_w(const float* __restrict__ in,
                                                f16* __restrict__ oh, f16* __restrict__ ol,
                                                int R, int C) {
  __shared__ float tile[64][65];
  int rtiles = R >> 6;
  int rt = blockIdx.x % rtiles, ct = blockIdx.x / rtiles;
  int r0 = rt << 6, c0 = ct << 6, t = threadIdx.x;
#pragma unroll
  for (int i = 0; i < 16; ++i) {
    int e = t + i * 256; int r = e >> 6, c = e & 63;
    tile[r][c] = in[(size_t)(r0 + r) * C + c0 + c];
  }
  __syncthreads();
#pragma unroll
  for (int i = 0; i < 16; ++i) {
    int e = t + i * 256; int c = e >> 6, r = e & 63;
    float v = tile[r][c];
    size_t idx = (size_t)(c0 + c) * R + r0 + r;
    if constexpr (MODE == 0) {
      v *= 256.0f;
      f16 h = (f16)v;
      oh[idx] = h;
      ol[idx] = (f16)(v - (float)h);
    } else {
      oh[idx] = (f16)v;
    }
  }
}

// ---------------- T1: XE[b][256][1024] = E^T X_b, exact fp32 VALU ----------------
// grid 512: tile [32 kr][64 dd]; block 256 thr, per-thread 2kr x 4dd.
__global__ __launch_bounds__(256) void k_xe(const float* __restrict__ x,
                                            const float* __restrict__ E,
                                            float* __restrict__ XE) {
  __shared__ __align__(16) float sX[32][64];
  __shared__ __align__(16) float sE[32][32];
  int bx = blockIdx.x;
  int ddt = bx & 15, krt = (bx >> 4) & 7, b = bx >> 7;
  int kr0 = krt * 32, dd0 = ddt * 64;
  int t = threadIdx.x;
  int ddg = t & 15, krg = t >> 4;   // 16 dd-groups x 16 kr-groups
  f32x4 a0 = {0,0,0,0}, a1 = {0,0,0,0};
  for (int s0 = 0; s0 < SEQ; s0 += 32) {
#pragma unroll
    for (int i = 0; i < 2; ++i) {
      int c = t + i * 256; int s = c >> 4, c16 = c & 15;
      *(f32x4*)&sX[s][c16 * 4] =
          *(const f32x4*)&x[((size_t)(b * SEQ) + s0 + s) * DIM + dd0 + c16 * 4];
    }
    {
      int s = t >> 3, k4 = (t & 7) * 4;
      *(f32x4*)&sE[s][k4] = *(const f32x4*)&E[(size_t)(s0 + s) * KRNK + kr0 + k4];
    }
    __syncthreads();
#pragma unroll
    for (int s = 0; s < 32; ++s) {
      f32x4 xv = *(const f32x4*)&sX[s][ddg * 4];
      float e0 = sE[s][krg * 2], e1 = sE[s][krg * 2 + 1];
      a0 += e0 * xv;
      a1 += e1 * xv;
    }
    __syncthreads();
  }
  size_t base = ((size_t)(b * KRNK) + kr0 + krg * 2) * DIM + dd0 + ddg * 4;
  *(f32x4*)&XE[base] = a0;
  *(f32x4*)&XE[base + DIM] = a1;
}

// ---------------- split-fp16 GEMM core: C = A(f32, hi/lo split) * (Bh+Bl)^T, 128x128, BK=64 ----
// 3 terms: ah*bh + ah*bl + al*bh. B is pre-scaled x256; caller descales epilogue.
static __device__ __forceinline__ void gemm_split_core(
    const float* __restrict__ A, int lda,
    const f16* __restrict__ Bh, const f16* __restrict__ Bl, int ldb,
    int bm, int bn, int K,
    f16* sAh, f16* sAl, f16* sBh, f16* sBl, f32x4 acc[4][4]) {
  const int t = threadIdx.x;
  const int lane = t & 63, w = t >> 6;
  const int wr = w >> 1, wc = w & 1;
  const int l15 = lane & 15, hi = lane >> 4;
  const f32x4 zero = {0.f, 0.f, 0.f, 0.f};
#pragma unroll
  for (int m = 0; m < 4; ++m)
#pragma unroll
    for (int n = 0; n < 4; ++n) acc[m][n] = zero;

  for (int kk = 0; kk < K; kk += 64) {
#pragma unroll
    for (int i = 0; i < 4; ++i) {
      int c = t + i * 256;            // 1024 chunks of 8 elems
      int row = c >> 3, cc = c & 7;
      const float* src = A + (size_t)(bm + row) * lda + kk + cc * 8;
      f32x4 f0 = *(const f32x4*)src;
      f32x4 f1 = *(const f32x4*)(src + 4);
      f16x8 h, l;
#pragma unroll
      for (int j = 0; j < 4; ++j) {
        f16 hh = (f16)f0[j]; h[j] = hh; l[j] = (f16)(f0[j] - (float)hh);
      }
#pragma unroll
      for (int j = 0; j < 4; ++j) {
        f16 hh = (f16)f1[j]; h[4 + j] = hh; l[4 + j] = (f16)(f1[j] - (float)hh);
      }
      *(f16x8*)&sAh[c * 8] = h;
      *(f16x8*)&sAl[c * 8] = l;
    }
#pragma unroll
    for (int i = 0; i < 4; ++i) {
      int c = t + i * 256;
      int row = c >> 3, cc = c & 7;
      size_t g = (size_t)(bn + row) * ldb + kk + cc * 8;
      glds16(Bh + g, &sBh[c * 8]);
      glds16(Bl + g, &sBl[c * 8]);
    }
    __syncthreads();

    f16x8 avh[4][2], avl[4][2], bvh[4][2], bvl[4][2];
#pragma unroll
    for (int m = 0; m < 4; ++m)
#pragma unroll
      for (int ks = 0; ks < 2; ++ks) {
        int off = (wr * 64 + m * 16 + l15) * 64 + ks * 32 + hi * 8;
        avh[m][ks] = *(const f16x8*)&sAh[off];
        avl[m][ks] = *(const f16x8*)&sAl[off];
      }
#pragma unroll
    for (int n = 0; n < 4; ++n)
#pragma unroll
      for (int ks = 0; ks < 2; ++ks) {
        int off = (wc * 64 + n * 16 + l15) * 64 + ks * 32 + hi * 8;
        bvh[n][ks] = *(const f16x8*)&sBh[off];
        bvl[n][ks] = *(const f16x8*)&sBl[off];
      }
#pragma unroll
    for (int m = 0; m < 4; ++m)
#pragma unroll
      for (int n = 0; n < 4; ++n)
#pragma unroll
        for (int ks = 0; ks < 2; ++ks) {
          acc[m][n] = __builtin_amdgcn_mfma_f32_16x16x32_f16(avl[m][ks], bvh[n][ks], acc[m][n], 0, 0, 0);
          acc[m][n] = __builtin_amdgcn_mfma_f32_16x16x32_f16(avh[m][ks], bvl[n][ks], acc[m][n], 0, 0, 0);
          acc[m][n] = __builtin_amdgcn_mfma_f32_16x16x32_f16(avh[m][ks], bvh[n][ks], acc[m][n], 0, 0, 0);
        }
    __syncthreads();
  }
}

// ---------------- GQ: q = x @ Wq (split, exact), store fp16 ----------------
__global__ __launch_bounds__(256) void k_gq(const float* __restrict__ x,
                                            const f16* __restrict__ Wph,
                                            const f16* __restrict__ Wpl,
                                            f16* __restrict__ q) {
  __shared__ __align__(16) f16 sAh[128 * 64], sAl[128 * 64];
  __shared__ __align__(16) f16 sBh[128 * 64], sBl[128 * 64];
  int bx = blockIdx.x;
  int mt = bx & 127, nt = bx >> 7;    // 128 x 8
  int bm = mt << 7, bn = nt << 7;
  f32x4 acc[4][4];
  gemm_split_core(x, DIM, Wph, Wpl, DIM, bm, bn, DIM, sAh, sAl, sBh, sBl, acc);
  const int t = threadIdx.x, lane = t & 63, w = t >> 6;
  const int wr = w >> 1, wc = w & 1, l15 = lane & 15, hi = lane >> 4;
#pragma unroll
  for (int m = 0; m < 4; ++m)
#pragma unroll
    for (int n = 0; n < 4; ++n)
#pragma unroll
      for (int r = 0; r < 4; ++r) {
        int row = bm + wr * 64 + m * 16 + hi * 4 + r;
        int col = bn + wc * 64 + n * 16 + l15;
        q[(size_t)row * DIM + col] = (f16)(acc[m][n][r] * (1.0f / 256.0f));
      }
}

// ---------------- T2: kp/vp = XE_b @ W{k,v} (split, exact) ----------------
__global__ __launch_bounds__(256) void k_t2(const float* __restrict__ XE,
                                            const f16* __restrict__ Wph,
                                            const f16* __restrict__ Wpl,
                                            f16* __restrict__ kph,
                                            f16* __restrict__ kpl,
                                            f16* __restrict__ vpt) {
  __shared__ __align__(16) f16 sAh[128 * 64], sAl[128 * 64];
  __shared__ __align__(16) f16 sBh[128 * 64], sBl[128 * 64];
  int bx = blockIdx.x;                 // 128 blocks
  int nt = bx & 7, mt = (bx >> 3) & 1, b = (bx >> 4) & 3, kv = bx >> 6;
  const float* A = XE + (size_t)b * KRNK * DIM;
  size_t wbase = (size_t)(DIM + kv * DIM) * DIM;   // Wk rows [1024,2048), Wv rows [2048,3072)
  f32x4 acc[4][4];
  gemm_split_core(A, DIM, Wph + wbase, Wpl + wbase, DIM, mt << 7, nt << 7, DIM,
                  sAh, sAl, sBh, sBl, acc);
  const int t = threadIdx.x, lane = t & 63, w = t >> 6;
  const int wr = w >> 1, wc = w & 1, l15 = lane & 15, hi = lane >> 4;
#pragma unroll
  for (int m = 0; m < 4; ++m)
#pragma unroll
    for (int n = 0; n < 4; ++n)
#pragma unroll
      for (int r = 0; r < 4; ++r) {
        int row = (mt << 7) + wr * 64 + m * 16 + hi * 4 + r;   // kr 0..255
        int col = (nt << 7) + wc * 64 + n * 16 + l15;          // dd 0..1023
        float s = acc[m][n][r] * (1.0f / 256.0f);
        if (!kv) {
          size_t idx = ((size_t)(b * KRNK + row)) * DIM + col;
          f16 h = (f16)s;
          kph[idx] = h;
          kpl[idx] = (f16)(s - (float)h);
        } else {
          vpt[((size_t)(b * DIM + col)) * KRNK + row] = (f16)s;
        }
      }
}

// ---------------- fused attention: scores (2-term) -> softmax -> PV ----------------
// block 256 (4 waves x 16 q rows); kp/vpt read directly from global (L2-resident).
__global__ __launch_bounds__(256) void k_attn(const f16* __restrict__ q,
                                              const f16* __restrict__ kph,
                                              const f16* __restrict__ kpl,
                                              const f16* __restrict__ vpt,
                                              f16* __restrict__ oattn) {
  __shared__ __align__(16) f16 sP[64 * KRNK];   // 32 KB
  int bx = blockIdx.x;
  int qb = bx & 63;
  int bh = bx >> 6;
  int b = bh >> 4, h = bh & 15;
  int t = threadIdx.x;
  int lane = t & 63, w = t >> 6;
  int l15 = lane & 15, hi = lane >> 4;

  // Q A-frags direct from global
  int seqrow = qb * 64 + w * 16 + l15;
  const f16* qg = q + ((size_t)(b * SEQ + seqrow)) * DIM + h * HD;
  f16x8 aq[2];
  aq[0] = *(const f16x8*)(qg + hi * 8);
  aq[1] = *(const f16x8*)(qg + 32 + hi * 8);

  const f32x4 zero = {0.f, 0.f, 0.f, 0.f};
  f32x4 s[16];
#pragma unroll
  for (int n = 0; n < 16; ++n) {
    s[n] = zero;
    const f16* kb = kph + ((size_t)(b * KRNK + n * 16 + l15)) * DIM + h * HD;
    const f16* lb = kpl + ((size_t)(b * KRNK + n * 16 + l15)) * DIM + h * HD;
#pragma unroll
    for (int ks = 0; ks < 2; ++ks) {
      f16x8 bh8 = *(const f16x8*)(kb + ks * 32 + hi * 8);
      f16x8 bl8 = *(const f16x8*)(lb + ks * 32 + hi * 8);
      s[n] = __builtin_amdgcn_mfma_f32_16x16x32_f16(aq[ks], bl8, s[n], 0, 0, 0);
      s[n] = __builtin_amdgcn_mfma_f32_16x16x32_f16(aq[ks], bh8, s[n], 0, 0, 0);
    }
  }

  // softmax over kr: in-reg over 16 tiles + shfl over lane bits 0-3
  const float scale = 0.125f;
  float mx[4], sminv[4];
#pragma unroll
  for (int r = 0; r < 4; ++r) {
    float m0 = s[0][r];
#pragma unroll
    for (int n = 1; n < 16; ++n) m0 = fmaxf(m0, s[n][r]);
#pragma unroll
    for (int d = 1; d <= 8; d <<= 1) m0 = fmaxf(m0, __shfl_xor(m0, d));
    mx[r] = m0;
  }
  float sm[4] = {0.f, 0.f, 0.f, 0.f};
#pragma unroll
  for (int n = 0; n < 16; ++n)
#pragma unroll
    for (int r = 0; r < 4; ++r) {
      float p = __expf((s[n][r] - mx[r]) * scale);
      s[n][r] = p;
      sm[r] += p;
    }
#pragma unroll
  for (int r = 0; r < 4; ++r) {
    float t2 = sm[r];
#pragma unroll
    for (int d = 1; d <= 8; d <<= 1) t2 += __shfl_xor(t2, d);
    sminv[r] = 1.0f / t2;
  }

  // write P (unnormalized, fp16) into sP, chunk-XOR swizzled [64 q][256 kr]
#pragma unroll
  for (int n = 0; n < 16; ++n)
#pragma unroll
    for (int r = 0; r < 4; ++r) {
      int qloc = w * 16 + hi * 4 + r;
      int kr = n * 16 + l15;
      int chunk = kr >> 3;
      sP[qloc * KRNK + ((chunk ^ (qloc & 7)) * 8) + (kr & 7)] = (f16)s[n][r];
    }
  __syncthreads();

  // PV: O[16q x 64hd] per wave; V frags direct from global
  f32x4 o[4];
#pragma unroll
  for (int n = 0; n < 4; ++n) o[n] = zero;
  int qloc = w * 16 + l15;
#pragma unroll
  for (int kc = 0; kc < 8; ++kc) {
    int chunk = kc * 4 + hi;
    f16x8 pa = *(const f16x8*)&sP[qloc * KRNK + ((chunk ^ (qloc & 7)) * 8)];
#pragma unroll
    for (int n = 0; n < 4; ++n) {
      const f16* vb = vpt + ((size_t)(b * DIM + h * HD + n * 16 + l15)) * KRNK + chunk * 8;
      f16x8 bv = *(const f16x8*)vb;
      o[n] = __builtin_amdgcn_mfma_f32_16x16x32_f16(pa, bv, o[n], 0, 0, 0);
    }
  }
  size_t obase = ((size_t)(b * SEQ + qb * 64)) * DIM + h * HD;
#pragma unroll
  for (int n = 0; n < 4; ++n)
#pragma unroll
    for (int r = 0; r < 4; ++r) {
      int qloc2 = w * 16 + hi * 4 + r;
      int hd = n * 16 + l15;
      oattn[obase + (size_t)qloc2 * DIM + hd] = (f16)(o[n][r] * sminv[r]);
    }
}

// ---------------- GO: out = oattn @ W_out + b_out (fp16 single, fp32 out) ----------------
__global__ __launch_bounds__(256) void k_go(const f16* __restrict__ oattn,
                                            const f16* __restrict__ WoT,
                                            const float* __restrict__ bias,
                                            float* __restrict__ out) {
  __shared__ __align__(16) f16 sA[128 * 64];
  __shared__ __align__(16) f16 sB[128 * 64];
  int bx = blockIdx.x;
  int mt = bx & 127, nt = bx >> 7;   // 128 x 8
  int bm = mt << 7, bn = nt << 7;
  const int t = threadIdx.x;
  const int lane = t & 63, w = t >> 6;
  const int wr = w >> 1, wc = w & 1, l15 = lane & 15, hi = lane >> 4;
  const f32x4 zero = {0.f, 0.f, 0.f, 0.f};
  f32x4 acc[4][4];
#pragma unroll
  for (int m = 0; m < 4; ++m)
#pragma unroll
    for (int n = 0; n < 4; ++n) acc[m][n] = zero;

  for (int kk = 0; kk < DIM; kk += 64) {
#pragma unroll
    for (int i = 0; i < 4; ++i) {
      int c = t + i * 256;
      int row = c >> 3, cc = c & 7;
      glds16(oattn + (size_t)(bm + row) * DIM + kk + cc * 8, &sA[c * 8]);
      glds16(WoT + (size_t)(bn + row) * DIM + kk + cc * 8, &sB[c * 8]);
    }
    __syncthreads();
    f16x8 av[4][2], bv[4][2];
#pragma unroll
    for (int m = 0; m < 4; ++m)
#pragma unroll
      for (int ks = 0; ks < 2; ++ks)
        av[m][ks] = *(const f16x8*)&sA[(wr * 64 + m * 16 + l15) * 64 + ks * 32 + hi * 8];
#pragma unroll
    for (int n = 0; n < 4; ++n)
#pragma unroll
      for (int ks = 0; ks < 2; ++ks)
        bv[n][ks] = *(const f16x8*)&sB[(wc * 64 + n * 16 + l15) * 64 + ks * 32 + hi * 8];
#pragma unroll
    for (int m = 0; m < 4; ++m)
#pragma unroll
      for (int n = 0; n < 4; ++n)
#pragma unroll
        for (int ks = 0; ks < 2; ++ks)
          acc[m][n] = __builtin_amdgcn_mfma_f32_16x16x32_f16(av[m][ks], bv[n][ks], acc[m][n], 0, 0, 0);
    __syncthreads();
  }
#pragma unroll
  for (int m = 0; m < 4; ++m)
#pragma unroll
    for (int n = 0; n < 4; ++n)
#pragma unroll
      for (int r = 0; r < 4; ++r) {
        int row = bm + wr * 64 + m * 16 + hi * 4 + r;
        int col = bn + wc * 64 + n * 16 + l15;
        out[(size_t)row * DIM + col] = acc[m][n][r] + bias[col];
      }
}

extern "C" void kernel_launch(void* const* d_in, const int* in_sizes, int n_in,
                              void* d_out, int out_size, void* d_ws, size_t ws_size,
                              hipStream_t stream) {
  const float* x    = (const float*)d_in[0];
  const float* Wqkv = (const float*)d_in[1];
  const float* E    = (const float*)d_in[2];
  const float* Wout = (const float*)d_in[3];
  const float* bout = (const float*)d_in[4];
  float* out = (float*)d_out;

  char* p = (char*)d_ws;
  float* XE  = (float*)p;  p += (size_t)4 * NB * KRNK * DIM;     //  4.19 MB fp32
  f16* Wph   = (f16*)p;    p += (size_t)2 * 3 * DIM * DIM;       //  6.29 MB
  f16* Wpl   = (f16*)p;    p += (size_t)2 * 3 * DIM * DIM;
  f16* WoT   = (f16*)p;    p += (size_t)2 * DIM * DIM;
  f16* q     = (f16*)p;    p += (size_t)2 * ROWS * DIM;          // 33.55 MB
  f16* kph   = (f16*)p;    p += (size_t)2 * NB * KRNK * DIM;
  f16* kpl   = (f16*)p;    p += (size_t)2 * NB * KRNK * DIM;
  f16* vpt   = (f16*)p;    p += (size_t)2 * NB * DIM * KRNK;
  f16* oattn = (f16*)p;    p += (size_t)2 * ROWS * DIM;          // 33.55 MB
  size_t need = (size_t)(p - (char*)d_ws);
  if (ws_size < need) return;   // fail-safe: zero output signals ws too small

  k_prep_w<0><<<(DIM / 64) * (3 * DIM / 64), 256, 0, stream>>>(Wqkv, Wph, Wpl, DIM, 3 * DIM);
  k_prep_w<1><<<(DIM / 64) * (DIM / 64), 256, 0, stream>>>(Wout, WoT, nullptr, DIM, DIM);
  k_xe<<<512, 256, 0, stream>>>(x, E, XE);
  k_gq<<<128 * 8, 256, 0, stream>>>(x, Wph, Wpl, q);
  k_t2<<<128, 256, 0, stream>>>(XE, Wph, Wpl, kph, kpl, vpt);
  k_attn<<<64 * 64, 256, 0, stream>>>(q, kph, kpl, vpt, oattn);
  k_go<<<128 * 8, 256, 0, stream>>>(oattn, WoT, bout, out);
}

// Round 3
// 499.020 us; speedup vs baseline: 1.1602x; 1.1602x over previous
//
#include <hip/hip_runtime.h>
#include <hip/hip_bf16.h>

typedef _Float16 f16;
typedef __attribute__((ext_vector_type(4))) _Float16 f16x4;
typedef __attribute__((ext_vector_type(8))) _Float16 f16x8;
typedef __attribute__((ext_vector_type(4))) float f32x4;

#define DIM 1024
#define SEQ 4096
#define KRNK 256
#define NH 16
#define HD 64
#define NB 4
#define ROWS (NB*SEQ)   // 16384

typedef const void __attribute__((address_space(1))) as1cv;
typedef void __attribute__((address_space(3))) as3v;

static __device__ __forceinline__ void glds16(const void* g, void* l) {
  __builtin_amdgcn_global_load_lds((as1cv*)g, (as3v*)l, 16, 0, 0);
}

// ---------------- W prep: transpose fp32 -> fp16 (MODE 0: scaled x256 hi/lo; 1: single) ----
template<int MODE>
__global__ __launch_bounds__(256) void k_prep_w(const float* __restrict__ in,
                                                f16* __restrict__ oh, f16* __restrict__ ol,
                                                int R, int C) {
  __shared__ float tile[64][65];
  int rtiles = R >> 6;
  int rt = blockIdx.x % rtiles, ct = blockIdx.x / rtiles;
  int r0 = rt << 6, c0 = ct << 6, t = threadIdx.x;
#pragma unroll
  for (int i = 0; i < 16; ++i) {
    int e = t + i * 256; int r = e >> 6, c = e & 63;
    tile[r][c] = in[(size_t)(r0 + r) * C + c0 + c];
  }
  __syncthreads();
#pragma unroll
  for (int i = 0; i < 16; ++i) {
    int e = t + i * 256; int c = e >> 6, r = e & 63;
    float v = tile[r][c];
    size_t idx = (size_t)(c0 + c) * R + r0 + r;
    if constexpr (MODE == 0) {
      v *= 256.0f;
      f16 h = (f16)v;
      oh[idx] = h;
      ol[idx] = (f16)(v - (float)h);
    } else {
      oh[idx] = (f16)v;
    }
  }
}

// ---------------- transpose+split prep: in[R][C] f32 -> oth/otl[C][R] f16 (h/l), opt oh[R][C] ----
template<bool WH>
__global__ __launch_bounds__(256) void k_tsplit(const float* __restrict__ in,
                                                f16* __restrict__ oh,
                                                f16* __restrict__ oth,
                                                f16* __restrict__ otl,
                                                int R, int C) {
  __shared__ float tile[64][65];
  int rtiles = R >> 6;
  int rt = blockIdx.x % rtiles, ct = blockIdx.x / rtiles;
  int r0 = rt << 6, c0 = ct << 6, t = threadIdx.x;
  int cq = (t & 15) * 4, rr = t >> 4;
#pragma unroll
  for (int i = 0; i < 4; ++i) {
    int r = rr + i * 16;
    f32x4 v = *(const f32x4*)&in[(size_t)(r0 + r) * C + c0 + cq];
    tile[r][cq] = v[0]; tile[r][cq + 1] = v[1];
    tile[r][cq + 2] = v[2]; tile[r][cq + 3] = v[3];
    if constexpr (WH) {
      f16x4 h = {(f16)v[0], (f16)v[1], (f16)v[2], (f16)v[3]};
      *(f16x4*)&oh[(size_t)(r0 + r) * C + c0 + cq] = h;
    }
  }
  __syncthreads();
  int d4 = (t >> 4) * 4, sq = (t & 15) * 4;
#pragma unroll
  for (int j = 0; j < 4; ++j) {
    f16x4 h4, l4;
#pragma unroll
    for (int k = 0; k < 4; ++k) {
      float v = tile[sq + k][d4 + j];
      f16 h = (f16)v;
      h4[k] = h;
      l4[k] = (f16)(v - (float)h);
    }
    size_t idx = (size_t)(c0 + d4 + j) * R + r0 + sq;
    *(f16x4*)&oth[idx] = h4;
    *(f16x4*)&otl[idx] = l4;
  }
}

// ---------------- generic 128xNT fp16 MFMA core, BK=64, 4 waves (2x2) ----------------
// C = (Ah[+Al]) * (Bh[+Bl])^T. A:[M][K] row-major, Bt:[N][K] row-major, all f16.
// terms: ASPL&&BSPL -> ah*bh+ah*bl+al*bh ; BSPL only -> ah*bh+ah*bl ; else ah*bh.
template<bool ASPL, bool BSPL, int NT>
static __device__ __forceinline__ void mm_core(
    const f16* __restrict__ Ah, const f16* __restrict__ Al, int lda,
    const f16* __restrict__ Bh, const f16* __restrict__ Bl, int ldb,
    int bm, int bn, int K,
    f16* sAh, f16* sAl, f16* sBh, f16* sBl,
    f32x4 (&acc)[4][NT / 32]) {
  constexpr int NREP = NT / 32;
  constexpr int BI = NT / 32;           // B staging iters (chunks = NT*8 / 256)
  const int t = threadIdx.x;
  const int lane = t & 63, w = t >> 6;
  const int wr = w >> 1, wc = w & 1;
  const int l15 = lane & 15, hi = lane >> 4;
  const f32x4 zero = {0.f, 0.f, 0.f, 0.f};
#pragma unroll
  for (int m = 0; m < 4; ++m)
#pragma unroll
    for (int n = 0; n < NREP; ++n) acc[m][n] = zero;

  for (int kk = 0; kk < K; kk += 64) {
#pragma unroll
    for (int i = 0; i < 4; ++i) {
      int c = t + i * 256;
      int row = c >> 3, cc = c & 7;
      size_t g = (size_t)(bm + row) * lda + kk + cc * 8;
      glds16(Ah + g, &sAh[c * 8]);
      if constexpr (ASPL) glds16(Al + g, &sAl[c * 8]);
    }
#pragma unroll
    for (int i = 0; i < BI; ++i) {
      int c = t + i * 256;
      int row = c >> 3, cc = c & 7;
      size_t g = (size_t)(bn + row) * ldb + kk + cc * 8;
      glds16(Bh + g, &sBh[c * 8]);
      if constexpr (BSPL) glds16(Bl + g, &sBl[c * 8]);
    }
    __syncthreads();

    f16x8 avh[4][2], avl[4][2], bvh[NREP][2], bvl[NREP][2];
#pragma unroll
    for (int m = 0; m < 4; ++m)
#pragma unroll
      for (int ks = 0; ks < 2; ++ks) {
        int off = (wr * 64 + m * 16 + l15) * 64 + ks * 32 + hi * 8;
        avh[m][ks] = *(const f16x8*)&sAh[off];
        if constexpr (ASPL) avl[m][ks] = *(const f16x8*)&sAl[off];
      }
#pragma unroll
    for (int n = 0; n < NREP; ++n)
#pragma unroll
      for (int ks = 0; ks < 2; ++ks) {
        int off = (wc * (NT / 2) + n * 16 + l15) * 64 + ks * 32 + hi * 8;
        bvh[n][ks] = *(const f16x8*)&sBh[off];
        if constexpr (BSPL) bvl[n][ks] = *(const f16x8*)&sBl[off];
      }
#pragma unroll
    for (int m = 0; m < 4; ++m)
#pragma unroll
      for (int n = 0; n < NREP; ++n)
#pragma unroll
        for (int ks = 0; ks < 2; ++ks) {
          if constexpr (ASPL && BSPL) {
            acc[m][n] = __builtin_amdgcn_mfma_f32_16x16x32_f16(avl[m][ks], bvh[n][ks], acc[m][n], 0, 0, 0);
            acc[m][n] = __builtin_amdgcn_mfma_f32_16x16x32_f16(avh[m][ks], bvl[n][ks], acc[m][n], 0, 0, 0);
          } else if constexpr (BSPL) {
            acc[m][n] = __builtin_amdgcn_mfma_f32_16x16x32_f16(avh[m][ks], bvl[n][ks], acc[m][n], 0, 0, 0);
          }
          acc[m][n] = __builtin_amdgcn_mfma_f32_16x16x32_f16(avh[m][ks], bvh[n][ks], acc[m][n], 0, 0, 0);
        }
    __syncthreads();
  }
}

// ---------------- XE = E^T X  (per batch; A=Et split, B=Xt split, 3 terms) ----------------
__global__ __launch_bounds__(256) void k_xe2(const f16* __restrict__ Eth,
                                             const f16* __restrict__ Etl,
                                             const f16* __restrict__ xth,
                                             const f16* __restrict__ xtl,
                                             f16* __restrict__ XEh,
                                             f16* __restrict__ XEl) {
  __shared__ __align__(16) f16 sAh[128 * 64], sAl[128 * 64];
  __shared__ __align__(16) f16 sBh[64 * 64], sBl[64 * 64];
  int bx = blockIdx.x;                     // 128: nt(16) x mt(2) x b(4)
  int nt = bx & 15, mt = (bx >> 4) & 1, b = bx >> 5;
  int bm = mt << 7, bn = nt << 6;
  f32x4 acc[4][2];
  mm_core<true, true, 64>(Eth, Etl, SEQ, xth + (size_t)b * SEQ, xtl + (size_t)b * SEQ, ROWS,
                          bm, bn, SEQ, sAh, sAl, sBh, sBl, acc);
  const int t = threadIdx.x, lane = t & 63, w = t >> 6;
  const int wr = w >> 1, wc = w & 1, l15 = lane & 15, hi = lane >> 4;
#pragma unroll
  for (int m = 0; m < 4; ++m)
#pragma unroll
    for (int n = 0; n < 2; ++n)
#pragma unroll
      for (int r = 0; r < 4; ++r) {
        int kr = bm + wr * 64 + m * 16 + hi * 4 + r;
        int dd = bn + wc * 32 + n * 16 + l15;
        float s = acc[m][n][r];
        size_t idx = ((size_t)(b * KRNK + kr)) * DIM + dd;
        f16 h = (f16)s;
        XEh[idx] = h;
        XEl[idx] = (f16)(s - (float)h);
      }
}

// ---------------- GQ: q = xh @ (Wqh+Wql)  (2 terms), store fp16 ----------------
__global__ __launch_bounds__(256) void k_gq(const f16* __restrict__ xh,
                                            const f16* __restrict__ Wph,
                                            const f16* __restrict__ Wpl,
                                            f16* __restrict__ q) {
  __shared__ __align__(16) f16 sAh[128 * 64];
  __shared__ __align__(16) f16 sBh[128 * 64], sBl[128 * 64];
  int bx = blockIdx.x;
  int mt = bx & 127, nt = bx >> 7;    // 128 x 8
  int bm = mt << 7, bn = nt << 7;
  f32x4 acc[4][4];
  mm_core<false, true, 128>(xh, nullptr, DIM, Wph, Wpl, DIM, bm, bn, DIM,
                            sAh, nullptr, sBh, sBl, acc);
  const int t = threadIdx.x, lane = t & 63, w = t >> 6;
  const int wr = w >> 1, wc = w & 1, l15 = lane & 15, hi = lane >> 4;
#pragma unroll
  for (int m = 0; m < 4; ++m)
#pragma unroll
    for (int n = 0; n < 4; ++n)
#pragma unroll
      for (int r = 0; r < 4; ++r) {
        int row = bm + wr * 64 + m * 16 + hi * 4 + r;
        int col = bn + wc * 64 + n * 16 + l15;
        q[(size_t)row * DIM + col] = (f16)(acc[m][n][r] * (1.0f / 256.0f));
      }
}

// ---------------- T2: kp/vp = (XEh+XEl) @ (W{k,v}h+l)  (3 terms) ----------------
__global__ __launch_bounds__(256) void k_t2(const f16* __restrict__ XEh,
                                            const f16* __restrict__ XEl,
                                            const f16* __restrict__ Wph,
                                            const f16* __restrict__ Wpl,
                                            f16* __restrict__ kph,
                                            f16* __restrict__ kpl,
                                            f16* __restrict__ vpt) {
  __shared__ __align__(16) f16 sAh[128 * 64], sAl[128 * 64];
  __shared__ __align__(16) f16 sBh[128 * 64], sBl[128 * 64];
  int bx = blockIdx.x;                 // 128: nt(8) x mt(2) x b(4) x kv(2)
  int nt = bx & 7, mt = (bx >> 3) & 1, b = (bx >> 4) & 3, kv = bx >> 6;
  size_t abase = (size_t)b * KRNK * DIM;
  size_t wbase = (size_t)(DIM + kv * DIM) * DIM;
  f32x4 acc[4][4];
  mm_core<true, true, 128>(XEh + abase, XEl + abase, DIM, Wph + wbase, Wpl + wbase, DIM,
                           mt << 7, nt << 7, DIM, sAh, sAl, sBh, sBl, acc);
  const int t = threadIdx.x, lane = t & 63, w = t >> 6;
  const int wr = w >> 1, wc = w & 1, l15 = lane & 15, hi = lane >> 4;
#pragma unroll
  for (int m = 0; m < 4; ++m)
#pragma unroll
    for (int n = 0; n < 4; ++n)
#pragma unroll
      for (int r = 0; r < 4; ++r) {
        int row = (mt << 7) + wr * 64 + m * 16 + hi * 4 + r;   // kr
        int col = (nt << 7) + wc * 64 + n * 16 + l15;          // dd
        float s = acc[m][n][r] * (1.0f / 256.0f);
        if (!kv) {
          size_t idx = ((size_t)(b * KRNK + row)) * DIM + col;
          f16 h = (f16)s;
          kph[idx] = h;
          kpl[idx] = (f16)(s - (float)h);
        } else {
          vpt[((size_t)(b * DIM + col)) * KRNK + row] = (f16)s;
        }
      }
}

// ---------------- fused attention: scores (2-term) -> softmax -> PV ----------------
__global__ __launch_bounds__(256) void k_attn(const f16* __restrict__ q,
                                              const f16* __restrict__ kph,
                                              const f16* __restrict__ kpl,
                                              const f16* __restrict__ vpt,
                                              f16* __restrict__ oattn) {
  __shared__ __align__(16) f16 sP[64 * KRNK];   // 32 KB
  int bx = blockIdx.x;
  int qb = bx & 63;
  int bh = bx >> 6;
  int b = bh >> 4, h = bh & 15;
  int t = threadIdx.x;
  int lane = t & 63, w = t >> 6;
  int l15 = lane & 15, hi = lane >> 4;

  int seqrow = qb * 64 + w * 16 + l15;
  const f16* qg = q + ((size_t)(b * SEQ + seqrow)) * DIM + h * HD;
  f16x8 aq[2];
  aq[0] = *(const f16x8*)(qg + hi * 8);
  aq[1] = *(const f16x8*)(qg + 32 + hi * 8);

  const f32x4 zero = {0.f, 0.f, 0.f, 0.f};
  f32x4 s[16];
#pragma unroll
  for (int n = 0; n < 16; ++n) {
    s[n] = zero;
    const f16* kb = kph + ((size_t)(b * KRNK + n * 16 + l15)) * DIM + h * HD;
    const f16* lb = kpl + ((size_t)(b * KRNK + n * 16 + l15)) * DIM + h * HD;
#pragma unroll
    for (int ks = 0; ks < 2; ++ks) {
      f16x8 bh8 = *(const f16x8*)(kb + ks * 32 + hi * 8);
      f16x8 bl8 = *(const f16x8*)(lb + ks * 32 + hi * 8);
      s[n] = __builtin_amdgcn_mfma_f32_16x16x32_f16(aq[ks], bl8, s[n], 0, 0, 0);
      s[n] = __builtin_amdgcn_mfma_f32_16x16x32_f16(aq[ks], bh8, s[n], 0, 0, 0);
    }
  }

  const float scale = 0.125f;
  float mx[4], sminv[4];
#pragma unroll
  for (int r = 0; r < 4; ++r) {
    float m0 = s[0][r];
#pragma unroll
    for (int n = 1; n < 16; ++n) m0 = fmaxf(m0, s[n][r]);
#pragma unroll
    for (int d = 1; d <= 8; d <<= 1) m0 = fmaxf(m0, __shfl_xor(m0, d));
    mx[r] = m0;
  }
  float sm[4] = {0.f, 0.f, 0.f, 0.f};
#pragma unroll
  for (int n = 0; n < 16; ++n)
#pragma unroll
    for (int r = 0; r < 4; ++r) {
      float p = __expf((s[n][r] - mx[r]) * scale);
      s[n][r] = p;
      sm[r] += p;
    }
#pragma unroll
  for (int r = 0; r < 4; ++r) {
    float t2 = sm[r];
#pragma unroll
    for (int d = 1; d <= 8; d <<= 1) t2 += __shfl_xor(t2, d);
    sminv[r] = 1.0f / t2;
  }

#pragma unroll
  for (int n = 0; n < 16; ++n)
#pragma unroll
    for (int r = 0; r < 4; ++r) {
      int qloc = w * 16 + hi * 4 + r;
      int kr = n * 16 + l15;
      int chunk = kr >> 3;
      sP[qloc * KRNK + ((chunk ^ (qloc & 7)) * 8) + (kr & 7)] = (f16)s[n][r];
    }
  __syncthreads();

  f32x4 o[4];
#pragma unroll
  for (int n = 0; n < 4; ++n) o[n] = zero;
  int qloc = w * 16 + l15;
#pragma unroll
  for (int kc = 0; kc < 8; ++kc) {
    int chunk = kc * 4 + hi;
    f16x8 pa = *(const f16x8*)&sP[qloc * KRNK + ((chunk ^ (qloc & 7)) * 8)];
#pragma unroll
    for (int n = 0; n < 4; ++n) {
      const f16* vb = vpt + ((size_t)(b * DIM + h * HD + n * 16 + l15)) * KRNK + chunk * 8;
      f16x8 bv = *(const f16x8*)vb;
      o[n] = __builtin_amdgcn_mfma_f32_16x16x32_f16(pa, bv, o[n], 0, 0, 0);
    }
  }
  size_t obase = ((size_t)(b * SEQ + qb * 64)) * DIM + h * HD;
#pragma unroll
  for (int n = 0; n < 4; ++n)
#pragma unroll
    for (int r = 0; r < 4; ++r) {
      int qloc2 = w * 16 + hi * 4 + r;
      int hd = n * 16 + l15;
      oattn[obase + (size_t)qloc2 * DIM + hd] = (f16)(o[n][r] * sminv[r]);
    }
}

// ---------------- GO: out = oattn @ W_out + b_out (fp32 out) ----------------
__global__ __launch_bounds__(256) void k_go(const f16* __restrict__ oattn,
                                            const f16* __restrict__ WoT,
                                            const float* __restrict__ bias,
                                            float* __restrict__ out) {
  __shared__ __align__(16) f16 sA[128 * 64];
  __shared__ __align__(16) f16 sB[128 * 64];
  int bx = blockIdx.x;
  int mt = bx & 127, nt = bx >> 7;   // 128 x 8
  int bm = mt << 7, bn = nt << 7;
  f32x4 acc[4][4];
  mm_core<false, false, 128>(oattn, nullptr, DIM, WoT, nullptr, DIM, bm, bn, DIM,
                             sA, nullptr, sB, nullptr, acc);
  const int t = threadIdx.x, lane = t & 63, w = t >> 6;
  const int wr = w >> 1, wc = w & 1, l15 = lane & 15, hi = lane >> 4;
#pragma unroll
  for (int m = 0; m < 4; ++m)
#pragma unroll
    for (int n = 0; n < 4; ++n)
#pragma unroll
      for (int r = 0; r < 4; ++r) {
        int row = bm + wr * 64 + m * 16 + hi * 4 + r;
        int col = bn + wc * 64 + n * 16 + l15;
        out[(size_t)row * DIM + col] = acc[m][n][r] + bias[col];
      }
}

extern "C" void kernel_launch(void* const* d_in, const int* in_sizes, int n_in,
                              void* d_out, int out_size, void* d_ws, size_t ws_size,
                              hipStream_t stream) {
  const float* x    = (const float*)d_in[0];
  const float* Wqkv = (const float*)d_in[1];
  const float* E    = (const float*)d_in[2];
  const float* Wout = (const float*)d_in[3];
  const float* bout = (const float*)d_in[4];
  float* out = (float*)d_out;

  char* p = (char*)d_ws;
  f16* Wph = (f16*)p;  p += (size_t)2 * 3 * DIM * DIM;   //  6.29 MB
  f16* Wpl = (f16*)p;  p += (size_t)2 * 3 * DIM * DIM;
  f16* WoT = (f16*)p;  p += (size_t)2 * DIM * DIM;       //  2.10 MB
  f16* xh  = (f16*)p;  p += (size_t)2 * ROWS * DIM;      // 33.55 MB
  f16* xth = (f16*)p;  p += (size_t)2 * DIM * ROWS;      // 33.55 MB
  f16* xtl = (f16*)p;  p += (size_t)2 * DIM * ROWS;      // 33.55 MB
  f16* Eth = (f16*)p;  p += (size_t)2 * KRNK * SEQ;      //  2.10 MB
  f16* Etl = (f16*)p;  p += (size_t)2 * KRNK * SEQ;
  f16* XEh = (f16*)p;  p += (size_t)2 * NB * KRNK * DIM; //  2.10 MB
  f16* XEl = (f16*)p;  p += (size_t)2 * NB * KRNK * DIM;
  f16* kph = (f16*)p;  p += (size_t)2 * NB * KRNK * DIM;
  f16* kpl = (f16*)p;  p += (size_t)2 * NB * KRNK * DIM;
  f16* vpt = (f16*)p;  p += (size_t)2 * NB * DIM * KRNK;
  size_t need = (size_t)(p - (char*)d_ws);
  if (ws_size < need) return;   // fail-safe: zero output signals ws too small

  // aliases into xth/xtl (dead after k_xe2; k_gq/k_attn run after it)
  f16* q     = xth;
  f16* oattn = xtl;

  k_prep_w<0><<<(DIM / 64) * (3 * DIM / 64), 256, 0, stream>>>(Wqkv, Wph, Wpl, DIM, 3 * DIM);
  k_prep_w<1><<<(DIM / 64) * (DIM / 64), 256, 0, stream>>>(Wout, WoT, nullptr, DIM, DIM);
  k_tsplit<true><<<(ROWS / 64) * (DIM / 64), 256, 0, stream>>>(x, xh, xth, xtl, ROWS, DIM);
  k_tsplit<false><<<(SEQ / 64) * (KRNK / 64), 256, 0, stream>>>(E, nullptr, Eth, Etl, SEQ, KRNK);
  k_xe2<<<128, 256, 0, stream>>>(Eth, Etl, xth, xtl, XEh, XEl);
  k_gq<<<128 * 8, 256, 0, stream>>>(xh, Wph, Wpl, q);
  k_t2<<<128, 256, 0, stream>>>(XEh, XEl, Wph, Wpl, kph, kpl, vpt);
  k_attn<<<64 * 64, 256, 0, stream>>>(q, kph, kpl, vpt, oattn);
  k_go<<<128 * 8, 256, 0, stream>>>(oattn, WoT, bout, out);
}

// Round 4
// 368.111 us; speedup vs baseline: 1.5728x; 1.3556x over previous
//
#include <hip/hip_runtime.h>
#include <hip/hip_bf16.h>

typedef _Float16 f16;
typedef __attribute__((ext_vector_type(4))) _Float16 f16x4;
typedef __attribute__((ext_vector_type(8))) _Float16 f16x8;
typedef __attribute__((ext_vector_type(4))) float f32x4;

#define DIM 1024
#define SEQ 4096
#define KRNK 256
#define NH 16
#define HD 64
#define NB 4
#define ROWS (NB*SEQ)   // 16384

typedef const void __attribute__((address_space(1))) as1cv;
typedef void __attribute__((address_space(3))) as3v;

static __device__ __forceinline__ void glds16(const void* g, void* l) {
  __builtin_amdgcn_global_load_lds((as1cv*)g, (as3v*)l, 16, 0, 0);
}

// ---------------- W prep: transpose fp32 -> fp16 (MODE 0: scaled x256 hi/lo; 1: single) ----
template<int MODE>
__global__ __launch_bounds__(256) void k_prep_w(const float* __restrict__ in,
                                                f16* __restrict__ oh, f16* __restrict__ ol,
                                                int R, int C) {
  __shared__ float tile[64][65];
  int rtiles = R >> 6;
  int rt = blockIdx.x % rtiles, ct = blockIdx.x / rtiles;
  int r0 = rt << 6, c0 = ct << 6, t = threadIdx.x;
#pragma unroll
  for (int i = 0; i < 16; ++i) {
    int e = t + i * 256; int r = e >> 6, c = e & 63;
    tile[r][c] = in[(size_t)(r0 + r) * C + c0 + c];
  }
  __syncthreads();
#pragma unroll
  for (int i = 0; i < 16; ++i) {
    int e = t + i * 256; int c = e >> 6, r = e & 63;
    float v = tile[r][c];
    size_t idx = (size_t)(c0 + c) * R + r0 + r;
    if constexpr (MODE == 0) {
      v *= 256.0f;
      f16 h = (f16)v;
      oh[idx] = h;
      ol[idx] = (f16)(v - (float)h);
    } else {
      oh[idx] = (f16)v;
    }
  }
}

// ---------------- transpose+split prep: in[R][C] f32 -> oth/otl[C][R] f16 (h/l), opt oh[R][C] ----
template<bool WH>
__global__ __launch_bounds__(256) void k_tsplit(const float* __restrict__ in,
                                                f16* __restrict__ oh,
                                                f16* __restrict__ oth,
                                                f16* __restrict__ otl,
                                                int R, int C) {
  __shared__ float tile[64][65];
  int rtiles = R >> 6;
  int rt = blockIdx.x % rtiles, ct = blockIdx.x / rtiles;
  int r0 = rt << 6, c0 = ct << 6, t = threadIdx.x;
  int cq = (t & 15) * 4, rr = t >> 4;
#pragma unroll
  for (int i = 0; i < 4; ++i) {
    int r = rr + i * 16;
    f32x4 v = *(const f32x4*)&in[(size_t)(r0 + r) * C + c0 + cq];
    tile[r][cq] = v[0]; tile[r][cq + 1] = v[1];
    tile[r][cq + 2] = v[2]; tile[r][cq + 3] = v[3];
    if constexpr (WH) {
      f16x4 h = {(f16)v[0], (f16)v[1], (f16)v[2], (f16)v[3]};
      *(f16x4*)&oh[(size_t)(r0 + r) * C + c0 + cq] = h;
    }
  }
  __syncthreads();
  int d4 = (t >> 4) * 4, sq = (t & 15) * 4;
#pragma unroll
  for (int j = 0; j < 4; ++j) {
    f16x4 h4, l4;
#pragma unroll
    for (int k = 0; k < 4; ++k) {
      float v = tile[sq + k][d4 + j];
      f16 h = (f16)v;
      h4[k] = h;
      l4[k] = (f16)(v - (float)h);
    }
    size_t idx = (size_t)(c0 + d4 + j) * R + r0 + sq;
    *(f16x4*)&oth[idx] = h4;
    *(f16x4*)&otl[idx] = l4;
  }
}

// ---------------- generic 128xNT fp16 MFMA core, BK=64, 4 waves (2x2) ----------------
template<bool ASPL, bool BSPL, int NT>
static __device__ __forceinline__ void mm_core(
    const f16* __restrict__ Ah, const f16* __restrict__ Al, int lda,
    const f16* __restrict__ Bh, const f16* __restrict__ Bl, int ldb,
    int bm, int bn, int K,
    f16* sAh, f16* sAl, f16* sBh, f16* sBl,
    f32x4 (&acc)[4][NT / 32]) {
  constexpr int NREP = NT / 32;
  constexpr int BI = NT / 32;
  const int t = threadIdx.x;
  const int lane = t & 63, w = t >> 6;
  const int wr = w >> 1, wc = w & 1;
  const int l15 = lane & 15, hi = lane >> 4;
  const f32x4 zero = {0.f, 0.f, 0.f, 0.f};
#pragma unroll
  for (int m = 0; m < 4; ++m)
#pragma unroll
    for (int n = 0; n < NREP; ++n) acc[m][n] = zero;

  for (int kk = 0; kk < K; kk += 64) {
#pragma unroll
    for (int i = 0; i < 4; ++i) {
      int c = t + i * 256;
      int row = c >> 3, cc = c & 7;
      size_t g = (size_t)(bm + row) * lda + kk + cc * 8;
      glds16(Ah + g, &sAh[c * 8]);
      if constexpr (ASPL) glds16(Al + g, &sAl[c * 8]);
    }
#pragma unroll
    for (int i = 0; i < BI; ++i) {
      int c = t + i * 256;
      int row = c >> 3, cc = c & 7;
      size_t g = (size_t)(bn + row) * ldb + kk + cc * 8;
      glds16(Bh + g, &sBh[c * 8]);
      if constexpr (BSPL) glds16(Bl + g, &sBl[c * 8]);
    }
    __syncthreads();

    f16x8 avh[4][2], avl[4][2], bvh[NREP][2], bvl[NREP][2];
#pragma unroll
    for (int m = 0; m < 4; ++m)
#pragma unroll
      for (int ks = 0; ks < 2; ++ks) {
        int off = (wr * 64 + m * 16 + l15) * 64 + ks * 32 + hi * 8;
        avh[m][ks] = *(const f16x8*)&sAh[off];
        if constexpr (ASPL) avl[m][ks] = *(const f16x8*)&sAl[off];
      }
#pragma unroll
    for (int n = 0; n < NREP; ++n)
#pragma unroll
      for (int ks = 0; ks < 2; ++ks) {
        int off = (wc * (NT / 2) + n * 16 + l15) * 64 + ks * 32 + hi * 8;
        bvh[n][ks] = *(const f16x8*)&sBh[off];
        if constexpr (BSPL) bvl[n][ks] = *(const f16x8*)&sBl[off];
      }
#pragma unroll
    for (int m = 0; m < 4; ++m)
#pragma unroll
      for (int n = 0; n < NREP; ++n)
#pragma unroll
        for (int ks = 0; ks < 2; ++ks) {
          if constexpr (ASPL && BSPL) {
            acc[m][n] = __builtin_amdgcn_mfma_f32_16x16x32_f16(avl[m][ks], bvh[n][ks], acc[m][n], 0, 0, 0);
            acc[m][n] = __builtin_amdgcn_mfma_f32_16x16x32_f16(avh[m][ks], bvl[n][ks], acc[m][n], 0, 0, 0);
          } else if constexpr (BSPL) {
            acc[m][n] = __builtin_amdgcn_mfma_f32_16x16x32_f16(avh[m][ks], bvl[n][ks], acc[m][n], 0, 0, 0);
          }
          acc[m][n] = __builtin_amdgcn_mfma_f32_16x16x32_f16(avh[m][ks], bvh[n][ks], acc[m][n], 0, 0, 0);
        }
    __syncthreads();
  }
}

// ---------------- XE = E^T X  (per batch; A=Et split, B=Xt split, 3 terms) ----------------
__global__ __launch_bounds__(256) void k_xe2(const f16* __restrict__ Eth,
                                             const f16* __restrict__ Etl,
                                             const f16* __restrict__ xth,
                                             const f16* __restrict__ xtl,
                                             f16* __restrict__ XEh,
                                             f16* __restrict__ XEl) {
  __shared__ __align__(16) f16 sAh[128 * 64], sAl[128 * 64];
  __shared__ __align__(16) f16 sBh[64 * 64], sBl[64 * 64];
  int bx = blockIdx.x;
  int nt = bx & 15, mt = (bx >> 4) & 1, b = bx >> 5;
  int bm = mt << 7, bn = nt << 6;
  f32x4 acc[4][2];
  mm_core<true, true, 64>(Eth, Etl, SEQ, xth + (size_t)b * SEQ, xtl + (size_t)b * SEQ, ROWS,
                          bm, bn, SEQ, sAh, sAl, sBh, sBl, acc);
  const int t = threadIdx.x, lane = t & 63, w = t >> 6;
  const int wr = w >> 1, wc = w & 1, l15 = lane & 15, hi = lane >> 4;
#pragma unroll
  for (int m = 0; m < 4; ++m)
#pragma unroll
    for (int n = 0; n < 2; ++n)
#pragma unroll
      for (int r = 0; r < 4; ++r) {
        int kr = bm + wr * 64 + m * 16 + hi * 4 + r;
        int dd = bn + wc * 32 + n * 16 + l15;
        float s = acc[m][n][r];
        size_t idx = ((size_t)(b * KRNK + kr)) * DIM + dd;
        f16 h = (f16)s;
        XEh[idx] = h;
        XEl[idx] = (f16)(s - (float)h);
      }
}

// ---------------- GQ: q = xh @ (Wqh+Wql)  (2 terms), store fp16 ----------------
__global__ __launch_bounds__(256) void k_gq(const f16* __restrict__ xh,
                                            const f16* __restrict__ Wph,
                                            const f16* __restrict__ Wpl,
                                            f16* __restrict__ q) {
  __shared__ __align__(16) f16 sAh[128 * 64];
  __shared__ __align__(16) f16 sBh[128 * 64], sBl[128 * 64];
  int bx = blockIdx.x;
  int mt = bx & 127, nt = bx >> 7;
  int bm = mt << 7, bn = nt << 7;
  f32x4 acc[4][4];
  mm_core<false, true, 128>(xh, nullptr, DIM, Wph, Wpl, DIM, bm, bn, DIM,
                            sAh, nullptr, sBh, sBl, acc);
  const int t = threadIdx.x, lane = t & 63, w = t >> 6;
  const int wr = w >> 1, wc = w & 1, l15 = lane & 15, hi = lane >> 4;
#pragma unroll
  for (int m = 0; m < 4; ++m)
#pragma unroll
    for (int n = 0; n < 4; ++n)
#pragma unroll
      for (int r = 0; r < 4; ++r) {
        int row = bm + wr * 64 + m * 16 + hi * 4 + r;
        int col = bn + wc * 64 + n * 16 + l15;
        q[(size_t)row * DIM + col] = (f16)(acc[m][n][r] * (1.0f / 256.0f));
      }
}

// ---------------- T2: kp/vp = (XEh+XEl) @ (W{k,v}h+l)  (3 terms); K stores h only ----
__global__ __launch_bounds__(256) void k_t2(const f16* __restrict__ XEh,
                                            const f16* __restrict__ XEl,
                                            const f16* __restrict__ Wph,
                                            const f16* __restrict__ Wpl,
                                            f16* __restrict__ kph,
                                            f16* __restrict__ vpt) {
  __shared__ __align__(16) f16 sAh[128 * 64], sAl[128 * 64];
  __shared__ __align__(16) f16 sBh[128 * 64], sBl[128 * 64];
  int bx = blockIdx.x;
  int nt = bx & 7, mt = (bx >> 3) & 1, b = (bx >> 4) & 3, kv = bx >> 6;
  size_t abase = (size_t)b * KRNK * DIM;
  size_t wbase = (size_t)(DIM + kv * DIM) * DIM;
  f32x4 acc[4][4];
  mm_core<true, true, 128>(XEh + abase, XEl + abase, DIM, Wph + wbase, Wpl + wbase, DIM,
                           mt << 7, nt << 7, DIM, sAh, sAl, sBh, sBl, acc);
  const int t = threadIdx.x, lane = t & 63, w = t >> 6;
  const int wr = w >> 1, wc = w & 1, l15 = lane & 15, hi = lane >> 4;
#pragma unroll
  for (int m = 0; m < 4; ++m)
#pragma unroll
    for (int n = 0; n < 4; ++n)
#pragma unroll
      for (int r = 0; r < 4; ++r) {
        int row = (mt << 7) + wr * 64 + m * 16 + hi * 4 + r;   // kr
        int col = (nt << 7) + wc * 64 + n * 16 + l15;          // dd
        float s = acc[m][n][r] * (1.0f / 256.0f);
        if (!kv) kph[((size_t)(b * KRNK + row)) * DIM + col] = (f16)s;
        else     vpt[((size_t)(b * DIM + col)) * KRNK + row] = (f16)s;
      }
}

// ---------------- fused attention: async-staged scores -> softmax -> PV ----------------
// block 256 thr (4 waves x 16 q rows = 64 q rows), one (b,h); K/V chunks (64x64)
// double-buffered via global_load_lds with slot XOR-swizzle (pre-swizzled global src).
__global__ __launch_bounds__(256) void k_attn(const f16* __restrict__ q,
                                              const f16* __restrict__ kph,
                                              const f16* __restrict__ vpt,
                                              f16* __restrict__ oattn) {
  __shared__ __align__(16) f16 sBuf[2][64 * 64];   // 2 x 8 KB staging
  __shared__ __align__(16) f16 sP[64 * KRNK];      // 32 KB
  int bx0 = blockIdx.x;
  int swz = (bx0 & 7) * 512 + (bx0 >> 3);          // XCD-contiguous (4096 % 8 == 0)
  int qb = swz & 63;
  int bh = swz >> 6;
  int b = bh >> 4, h = bh & 15;
  int t = threadIdx.x;
  int lane = t & 63, w = t >> 6;
  int l15 = lane & 15, hi = lane >> 4;

  const f16* kbase = kph + ((size_t)(b * KRNK)) * DIM + h * HD;     // row kr, stride DIM
  const f16* vbase = vpt + ((size_t)(b * DIM + h * HD)) * KRNK;     // row hd, stride KRNK

  // stage 64x64 chunk; LDS slot sid holds global col16 = (sid&7) ^ (row&7)  [inverse==same XOR]
  auto stageK = [&](int c, int bufi) {
#pragma unroll
    for (int i = 0; i < 2; ++i) {
      int sid = w * 128 + i * 64 + lane;
      int kr = sid >> 3, sl = sid & 7;
      glds16(kbase + (size_t)(c * 64 + kr) * DIM + ((sl ^ (kr & 7)) * 8),
             &sBuf[bufi][sid * 8]);
    }
  };
  auto stageV = [&](int c, int bufi) {
#pragma unroll
    for (int i = 0; i < 2; ++i) {
      int sid = w * 128 + i * 64 + lane;
      int hd = sid >> 3, sl = sid & 7;
      glds16(vbase + (size_t)hd * KRNK + c * 64 + ((sl ^ (hd & 7)) * 8),
             &sBuf[bufi][sid * 8]);
    }
  };

  // Q A-frags direct from global (row per lane = l15; k = ks*32 + hi*8 + j)
  int seqrow = qb * 64 + w * 16 + l15;
  const f16* qg = q + ((size_t)(b * SEQ + seqrow)) * DIM + h * HD;
  f16x8 aq[2];
  aq[0] = *(const f16x8*)(qg + hi * 8);
  aq[1] = *(const f16x8*)(qg + 32 + hi * 8);

  const f32x4 zero = {0.f, 0.f, 0.f, 0.f};
  f32x4 s[16];

  stageK(0, 0);
#pragma unroll
  for (int c = 0; c < 4; ++c) {
    __syncthreads();                       // staged chunk c ready; prev reads drained
    if (c < 3) stageK(c + 1, (c + 1) & 1);
    else       stageV(0, 0);
#pragma unroll
    for (int n = 0; n < 4; ++n) {
      int nn = c * 4 + n;
      s[nn] = zero;
      int krl = n * 16 + l15;              // row within chunk
#pragma unroll
      for (int ks = 0; ks < 2; ++ks) {
        f16x8 bk = *(const f16x8*)&sBuf[c & 1][krl * 64 + (((ks * 4 + hi) ^ (krl & 7)) * 8)];
        s[nn] = __builtin_amdgcn_mfma_f32_16x16x32_f16(aq[ks], bk, s[nn], 0, 0, 0);
      }
    }
  }

  // softmax over kr (16 in-reg tiles + shfl_xor over lane bits 0-3)
  const float scale = 0.125f;
  float mx[4], sminv[4];
#pragma unroll
  for (int r = 0; r < 4; ++r) {
    float m0 = s[0][r];
#pragma unroll
    for (int n = 1; n < 16; ++n) m0 = fmaxf(m0, s[n][r]);
#pragma unroll
    for (int d = 1; d <= 8; d <<= 1) m0 = fmaxf(m0, __shfl_xor(m0, d));
    mx[r] = m0;
  }
  float sm[4] = {0.f, 0.f, 0.f, 0.f};
#pragma unroll
  for (int n = 0; n < 16; ++n)
#pragma unroll
    for (int r = 0; r < 4; ++r) {
      float p = __expf((s[n][r] - mx[r]) * scale);
      s[n][r] = p;
      sm[r] += p;
    }
#pragma unroll
  for (int r = 0; r < 4; ++r) {
    float t2 = sm[r];
#pragma unroll
    for (int d = 1; d <= 8; d <<= 1) t2 += __shfl_xor(t2, d);
    sminv[r] = 1.0f / t2;
  }

  // write P (unnormalized f16) into sP, chunk-XOR swizzled [64 q][256 kr]
#pragma unroll
  for (int n = 0; n < 16; ++n)
#pragma unroll
    for (int r = 0; r < 4; ++r) {
      int qloc = w * 16 + hi * 4 + r;
      int kr = n * 16 + l15;
      int chunk = kr >> 3;
      sP[qloc * KRNK + ((chunk ^ (qloc & 7)) * 8) + (kr & 7)] = (f16)s[n][r];
    }

  // PV: O[16q x 64hd] per wave; V chunks double-buffered
  f32x4 o[4];
#pragma unroll
  for (int n = 0; n < 4; ++n) o[n] = zero;
  int qloc = w * 16 + l15;
#pragma unroll
  for (int c = 0; c < 4; ++c) {
    __syncthreads();                       // V chunk c ready; sP writes visible (c==0)
    if (c < 3) stageV(c + 1, (c + 1) & 1);
#pragma unroll
    for (int sub = 0; sub < 2; ++sub) {
      int chunk = c * 8 + sub * 4 + hi;
      f16x8 pa = *(const f16x8*)&sP[qloc * KRNK + ((chunk ^ (qloc & 7)) * 8)];
#pragma unroll
      for (int n = 0; n < 4; ++n) {
        int hd = n * 16 + l15;
        f16x8 bv = *(const f16x8*)&sBuf[c & 1][hd * 64 + (((sub * 4 + hi) ^ (hd & 7)) * 8)];
        o[n] = __builtin_amdgcn_mfma_f32_16x16x32_f16(pa, bv, o[n], 0, 0, 0);
      }
    }
  }

  size_t obase = ((size_t)(b * SEQ + qb * 64)) * DIM + h * HD;
#pragma unroll
  for (int n = 0; n < 4; ++n)
#pragma unroll
    for (int r = 0; r < 4; ++r) {
      int qloc2 = w * 16 + hi * 4 + r;
      int hd = n * 16 + l15;
      oattn[obase + (size_t)qloc2 * DIM + hd] = (f16)(o[n][r] * sminv[r]);
    }
}

// ---------------- GO: out = oattn @ W_out + b_out (fp32 out) ----------------
__global__ __launch_bounds__(256) void k_go(const f16* __restrict__ oattn,
                                            const f16* __restrict__ WoT,
                                            const float* __restrict__ bias,
                                            float* __restrict__ out) {
  __shared__ __align__(16) f16 sA[128 * 64];
  __shared__ __align__(16) f16 sB[128 * 64];
  int bx = blockIdx.x;
  int mt = bx & 127, nt = bx >> 7;
  int bm = mt << 7, bn = nt << 7;
  f32x4 acc[4][4];
  mm_core<false, false, 128>(oattn, nullptr, DIM, WoT, nullptr, DIM, bm, bn, DIM,
                             sA, nullptr, sB, nullptr, acc);
  const int t = threadIdx.x, lane = t & 63, w = t >> 6;
  const int wr = w >> 1, wc = w & 1, l15 = lane & 15, hi = lane >> 4;
#pragma unroll
  for (int m = 0; m < 4; ++m)
#pragma unroll
    for (int n = 0; n < 4; ++n)
#pragma unroll
      for (int r = 0; r < 4; ++r) {
        int row = bm + wr * 64 + m * 16 + hi * 4 + r;
        int col = bn + wc * 64 + n * 16 + l15;
        out[(size_t)row * DIM + col] = acc[m][n][r] + bias[col];
      }
}

extern "C" void kernel_launch(void* const* d_in, const int* in_sizes, int n_in,
                              void* d_out, int out_size, void* d_ws, size_t ws_size,
                              hipStream_t stream) {
  const float* x    = (const float*)d_in[0];
  const float* Wqkv = (const float*)d_in[1];
  const float* E    = (const float*)d_in[2];
  const float* Wout = (const float*)d_in[3];
  const float* bout = (const float*)d_in[4];
  float* out = (float*)d_out;

  char* p = (char*)d_ws;
  f16* Wph = (f16*)p;  p += (size_t)2 * 3 * DIM * DIM;
  f16* Wpl = (f16*)p;  p += (size_t)2 * 3 * DIM * DIM;
  f16* WoT = (f16*)p;  p += (size_t)2 * DIM * DIM;
  f16* xh  = (f16*)p;  p += (size_t)2 * ROWS * DIM;
  f16* xth = (f16*)p;  p += (size_t)2 * DIM * ROWS;
  f16* xtl = (f16*)p;  p += (size_t)2 * DIM * ROWS;
  f16* Eth = (f16*)p;  p += (size_t)2 * KRNK * SEQ;
  f16* Etl = (f16*)p;  p += (size_t)2 * KRNK * SEQ;
  f16* XEh = (f16*)p;  p += (size_t)2 * NB * KRNK * DIM;
  f16* XEl = (f16*)p;  p += (size_t)2 * NB * KRNK * DIM;
  f16* kph = (f16*)p;  p += (size_t)2 * NB * KRNK * DIM;
  f16* vpt = (f16*)p;  p += (size_t)2 * NB * DIM * KRNK;
  size_t need = (size_t)(p - (char*)d_ws);
  if (ws_size < need) return;

  // aliases into xth/xtl (dead after k_xe2)
  f16* q     = xth;
  f16* oattn = xtl;

  k_prep_w<0><<<(DIM / 64) * (3 * DIM / 64), 256, 0, stream>>>(Wqkv, Wph, Wpl, DIM, 3 * DIM);
  k_prep_w<1><<<(DIM / 64) * (DIM / 64), 256, 0, stream>>>(Wout, WoT, nullptr, DIM, DIM);
  k_tsplit<true><<<(ROWS / 64) * (DIM / 64), 256, 0, stream>>>(x, xh, xth, xtl, ROWS, DIM);
  k_tsplit<false><<<(SEQ / 64) * (KRNK / 64), 256, 0, stream>>>(E, nullptr, Eth, Etl, SEQ, KRNK);
  k_xe2<<<128, 256, 0, stream>>>(Eth, Etl, xth, xtl, XEh, XEl);
  k_gq<<<128 * 8, 256, 0, stream>>>(xh, Wph, Wpl, q);
  k_t2<<<128, 256, 0, stream>>>(XEh, XEl, Wph, Wpl, kph, vpt);
  k_attn<<<64 * 64, 256, 0, stream>>>(q, kph, vpt, oattn);
  k_go<<<128 * 8, 256, 0, stream>>>(oattn, WoT, bout, out);
}

// Round 5
// 275.643 us; speedup vs baseline: 2.1004x; 1.3355x over previous
//
#include <hip/hip_runtime.h>
#include <hip/hip_bf16.h>

typedef _Float16 f16;
typedef __attribute__((ext_vector_type(4))) _Float16 f16x4;
typedef __attribute__((ext_vector_type(8))) _Float16 f16x8;
typedef __attribute__((ext_vector_type(4))) float f32x4;

#define DIM 1024
#define SEQ 4096
#define KRNK 256
#define NH 16
#define HD 64
#define NB 4
#define ROWS (NB*SEQ)   // 16384
#define NSPLIT 4

typedef const void __attribute__((address_space(1))) as1cv;
typedef void __attribute__((address_space(3))) as3v;

static __device__ __forceinline__ void glds16(const void* g, void* l) {
  __builtin_amdgcn_global_load_lds((as1cv*)g, (as3v*)l, 16, 0, 0);
}

// ---------------- W prep: transpose fp32 -> fp16 (MODE 0: scaled x256 hi/lo; 1: single) ----
template<int MODE>
__global__ __launch_bounds__(256) void k_prep_w(const float* __restrict__ in,
                                                f16* __restrict__ oh, f16* __restrict__ ol,
                                                int R, int C) {
  __shared__ float tile[64][65];
  int rtiles = R >> 6;
  int rt = blockIdx.x % rtiles, ct = blockIdx.x / rtiles;
  int r0 = rt << 6, c0 = ct << 6, t = threadIdx.x;
#pragma unroll
  for (int i = 0; i < 16; ++i) {
    int e = t + i * 256; int r = e >> 6, c = e & 63;
    tile[r][c] = in[(size_t)(r0 + r) * C + c0 + c];
  }
  __syncthreads();
#pragma unroll
  for (int i = 0; i < 16; ++i) {
    int e = t + i * 256; int c = e >> 6, r = e & 63;
    float v = tile[r][c];
    size_t idx = (size_t)(c0 + c) * R + r0 + r;
    if constexpr (MODE == 0) {
      v *= 256.0f;
      f16 h = (f16)v;
      oh[idx] = h;
      ol[idx] = (f16)(v - (float)h);
    } else {
      oh[idx] = (f16)v;
    }
  }
}

// ---------------- transpose+split prep: in[R][C] f32 -> oth/otl[C][R] f16 (h/l), opt oh[R][C] ----
template<bool WH>
__global__ __launch_bounds__(256) void k_tsplit(const float* __restrict__ in,
                                                f16* __restrict__ oh,
                                                f16* __restrict__ oth,
                                                f16* __restrict__ otl,
                                                int R, int C) {
  __shared__ float tile[64][65];
  int rtiles = R >> 6;
  int rt = blockIdx.x % rtiles, ct = blockIdx.x / rtiles;
  int r0 = rt << 6, c0 = ct << 6, t = threadIdx.x;
  int cq = (t & 15) * 4, rr = t >> 4;
#pragma unroll
  for (int i = 0; i < 4; ++i) {
    int r = rr + i * 16;
    f32x4 v = *(const f32x4*)&in[(size_t)(r0 + r) * C + c0 + cq];
    tile[r][cq] = v[0]; tile[r][cq + 1] = v[1];
    tile[r][cq + 2] = v[2]; tile[r][cq + 3] = v[3];
    if constexpr (WH) {
      f16x4 h = {(f16)v[0], (f16)v[1], (f16)v[2], (f16)v[3]};
      *(f16x4*)&oh[(size_t)(r0 + r) * C + c0 + cq] = h;
    }
  }
  __syncthreads();
  int d4 = (t >> 4) * 4, sq = (t & 15) * 4;
#pragma unroll
  for (int j = 0; j < 4; ++j) {
    f16x4 h4, l4;
#pragma unroll
    for (int k = 0; k < 4; ++k) {
      float v = tile[sq + k][d4 + j];
      f16 h = (f16)v;
      h4[k] = h;
      l4[k] = (f16)(v - (float)h);
    }
    size_t idx = (size_t)(c0 + d4 + j) * R + r0 + sq;
    *(f16x4*)&oth[idx] = h4;
    *(f16x4*)&otl[idx] = l4;
  }
}

// ---------------- generic 128xNT fp16 MFMA core, BK=64, 4 waves (2x2) ----------------
template<bool ASPL, bool BSPL, int NT>
static __device__ __forceinline__ void mm_core(
    const f16* __restrict__ Ah, const f16* __restrict__ Al, int lda,
    const f16* __restrict__ Bh, const f16* __restrict__ Bl, int ldb,
    int bm, int bn, int K,
    f16* sAh, f16* sAl, f16* sBh, f16* sBl,
    f32x4 (&acc)[4][NT / 32]) {
  constexpr int NREP = NT / 32;
  constexpr int BI = NT / 32;
  const int t = threadIdx.x;
  const int lane = t & 63, w = t >> 6;
  const int wr = w >> 1, wc = w & 1;
  const int l15 = lane & 15, hi = lane >> 4;
  const f32x4 zero = {0.f, 0.f, 0.f, 0.f};
#pragma unroll
  for (int m = 0; m < 4; ++m)
#pragma unroll
    for (int n = 0; n < NREP; ++n) acc[m][n] = zero;

  for (int kk = 0; kk < K; kk += 64) {
#pragma unroll
    for (int i = 0; i < 4; ++i) {
      int c = t + i * 256;
      int row = c >> 3, cc = c & 7;
      size_t g = (size_t)(bm + row) * lda + kk + cc * 8;
      glds16(Ah + g, &sAh[c * 8]);
      if constexpr (ASPL) glds16(Al + g, &sAl[c * 8]);
    }
#pragma unroll
    for (int i = 0; i < BI; ++i) {
      int c = t + i * 256;
      int row = c >> 3, cc = c & 7;
      size_t g = (size_t)(bn + row) * ldb + kk + cc * 8;
      glds16(Bh + g, &sBh[c * 8]);
      if constexpr (BSPL) glds16(Bl + g, &sBl[c * 8]);
    }
    __syncthreads();

    f16x8 avh[4][2], avl[4][2], bvh[NREP][2], bvl[NREP][2];
#pragma unroll
    for (int m = 0; m < 4; ++m)
#pragma unroll
      for (int ks = 0; ks < 2; ++ks) {
        int off = (wr * 64 + m * 16 + l15) * 64 + ks * 32 + hi * 8;
        avh[m][ks] = *(const f16x8*)&sAh[off];
        if constexpr (ASPL) avl[m][ks] = *(const f16x8*)&sAl[off];
      }
#pragma unroll
    for (int n = 0; n < NREP; ++n)
#pragma unroll
      for (int ks = 0; ks < 2; ++ks) {
        int off = (wc * (NT / 2) + n * 16 + l15) * 64 + ks * 32 + hi * 8;
        bvh[n][ks] = *(const f16x8*)&sBh[off];
        if constexpr (BSPL) bvl[n][ks] = *(const f16x8*)&sBl[off];
      }
#pragma unroll
    for (int m = 0; m < 4; ++m)
#pragma unroll
      for (int n = 0; n < NREP; ++n)
#pragma unroll
        for (int ks = 0; ks < 2; ++ks) {
          if constexpr (ASPL && BSPL) {
            acc[m][n] = __builtin_amdgcn_mfma_f32_16x16x32_f16(avl[m][ks], bvh[n][ks], acc[m][n], 0, 0, 0);
            acc[m][n] = __builtin_amdgcn_mfma_f32_16x16x32_f16(avh[m][ks], bvl[n][ks], acc[m][n], 0, 0, 0);
          } else if constexpr (BSPL) {
            acc[m][n] = __builtin_amdgcn_mfma_f32_16x16x32_f16(avh[m][ks], bvl[n][ks], acc[m][n], 0, 0, 0);
          }
          acc[m][n] = __builtin_amdgcn_mfma_f32_16x16x32_f16(avh[m][ks], bvh[n][ks], acc[m][n], 0, 0, 0);
        }
    __syncthreads();
  }
}

// ---------------- XE partials: split-K x4 over seq; fp32 partial out ----------------
__global__ __launch_bounds__(256) void k_xe2(const f16* __restrict__ Eth,
                                             const f16* __restrict__ Etl,
                                             const f16* __restrict__ xth,
                                             const f16* __restrict__ xtl,
                                             float* __restrict__ XEp) {
  __shared__ __align__(16) f16 sAh[128 * 64], sAl[128 * 64];
  __shared__ __align__(16) f16 sBh[64 * 64], sBl[64 * 64];
  int bx = blockIdx.x;                       // 512: nt(16) x mt(2) x b(4) x sp(4)
  int nt = bx & 15, mt = (bx >> 4) & 1, b = (bx >> 5) & 3, sp = bx >> 7;
  int bm = mt << 7, bn = nt << 6;
  int koff = sp * (SEQ / NSPLIT);
  f32x4 acc[4][2];
  mm_core<true, true, 64>(Eth + koff, Etl + koff, SEQ,
                          xth + (size_t)b * SEQ + koff, xtl + (size_t)b * SEQ + koff, ROWS,
                          bm, bn, SEQ / NSPLIT, sAh, sAl, sBh, sBl, acc);
  const int t = threadIdx.x, lane = t & 63, w = t >> 6;
  const int wr = w >> 1, wc = w & 1, l15 = lane & 15, hi = lane >> 4;
#pragma unroll
  for (int m = 0; m < 4; ++m)
#pragma unroll
    for (int n = 0; n < 2; ++n)
#pragma unroll
      for (int r = 0; r < 4; ++r) {
        int kr = bm + wr * 64 + m * 16 + hi * 4 + r;
        int dd = bn + wc * 32 + n * 16 + l15;
        XEp[(((size_t)sp * NB + b) * KRNK + kr) * DIM + dd] = acc[m][n][r];
      }
}

// ---------------- XE reduce: sum 4 partials, h/l split f16 out ----------------
__global__ __launch_bounds__(256) void k_xered(const float* __restrict__ XEp,
                                               f16* __restrict__ XEh,
                                               f16* __restrict__ XEl) {
  size_t i = (size_t)blockIdx.x * 256 + threadIdx.x;   // f32x4 index
  const size_t sstride = (size_t)NB * KRNK * DIM / 4;  // vec4s per split
  const f32x4* p = (const f32x4*)XEp;
  f32x4 s = p[i];
#pragma unroll
  for (int sp = 1; sp < NSPLIT; ++sp) s += p[i + sp * sstride];
  f16x4 h4, l4;
#pragma unroll
  for (int j = 0; j < 4; ++j) {
    f16 h = (f16)s[j];
    h4[j] = h;
    l4[j] = (f16)(s[j] - (float)h);
  }
  *(f16x4*)&XEh[i * 4] = h4;
  *(f16x4*)&XEl[i * 4] = l4;
}

// ---------------- GQ: q = xh @ Wqh  (1 term), store fp16 ----------------
__global__ __launch_bounds__(256) void k_gq(const f16* __restrict__ xh,
                                            const f16* __restrict__ Wph,
                                            f16* __restrict__ q) {
  __shared__ __align__(16) f16 sAh[128 * 64];
  __shared__ __align__(16) f16 sBh[128 * 64];
  int bx = blockIdx.x;
  int mt = bx & 127, nt = bx >> 7;
  int bm = mt << 7, bn = nt << 7;
  f32x4 acc[4][4];
  mm_core<false, false, 128>(xh, nullptr, DIM, Wph, nullptr, DIM, bm, bn, DIM,
                             sAh, nullptr, sBh, nullptr, acc);
  const int t = threadIdx.x, lane = t & 63, w = t >> 6;
  const int wr = w >> 1, wc = w & 1, l15 = lane & 15, hi = lane >> 4;
#pragma unroll
  for (int m = 0; m < 4; ++m)
#pragma unroll
    for (int n = 0; n < 4; ++n)
#pragma unroll
      for (int r = 0; r < 4; ++r) {
        int row = bm + wr * 64 + m * 16 + hi * 4 + r;
        int col = bn + wc * 64 + n * 16 + l15;
        q[(size_t)row * DIM + col] = (f16)(acc[m][n][r] * (1.0f / 256.0f));
      }
}

// ---------------- T2: kp/vp = (XEh+XEl) @ (W{k,v}h+l)  (3 terms), 64-wide tiles ----
__global__ __launch_bounds__(256) void k_t2(const f16* __restrict__ XEh,
                                            const f16* __restrict__ XEl,
                                            const f16* __restrict__ Wph,
                                            const f16* __restrict__ Wpl,
                                            f16* __restrict__ kph,
                                            f16* __restrict__ vpt) {
  __shared__ __align__(16) f16 sAh[128 * 64], sAl[128 * 64];
  __shared__ __align__(16) f16 sBh[64 * 64], sBl[64 * 64];
  int bx = blockIdx.x;                       // 256: nt(16) x mt(2) x b(4) x kv(2)
  int nt = bx & 15, mt = (bx >> 4) & 1, b = (bx >> 5) & 3, kv = bx >> 7;
  size_t abase = (size_t)b * KRNK * DIM;
  size_t wbase = (size_t)(DIM + kv * DIM) * DIM;
  f32x4 acc[4][2];
  mm_core<true, true, 64>(XEh + abase, XEl + abase, DIM, Wph + wbase, Wpl + wbase, DIM,
                          mt << 7, nt << 6, DIM, sAh, sAl, sBh, sBl, acc);
  const int t = threadIdx.x, lane = t & 63, w = t >> 6;
  const int wr = w >> 1, wc = w & 1, l15 = lane & 15, hi = lane >> 4;
#pragma unroll
  for (int m = 0; m < 4; ++m)
#pragma unroll
    for (int n = 0; n < 2; ++n)
#pragma unroll
      for (int r = 0; r < 4; ++r) {
        int row = (mt << 7) + wr * 64 + m * 16 + hi * 4 + r;   // kr
        int col = (nt << 6) + wc * 32 + n * 16 + l15;          // dd
        float s = acc[m][n][r] * (1.0f / 256.0f);
        if (!kv) kph[((size_t)(b * KRNK + row)) * DIM + col] = (f16)s;
        else     vpt[((size_t)(b * DIM + col)) * KRNK + row] = (f16)s;
      }
}

// ---------------- fused attention: async-staged scores -> softmax -> PV ----------------
__global__ __launch_bounds__(256) void k_attn(const f16* __restrict__ q,
                                              const f16* __restrict__ kph,
                                              const f16* __restrict__ vpt,
                                              f16* __restrict__ oattn) {
  __shared__ __align__(16) f16 sBuf[2][64 * 64];   // 2 x 8 KB staging
  __shared__ __align__(16) f16 sP[64 * KRNK];      // 32 KB
  int bx0 = blockIdx.x;
  int swz = (bx0 & 7) * 512 + (bx0 >> 3);          // XCD-contiguous (4096 % 8 == 0)
  int qb = swz & 63;
  int bh = swz >> 6;
  int b = bh >> 4, h = bh & 15;
  int t = threadIdx.x;
  int lane = t & 63, w = t >> 6;
  int l15 = lane & 15, hi = lane >> 4;

  const f16* kbase = kph + ((size_t)(b * KRNK)) * DIM + h * HD;
  const f16* vbase = vpt + ((size_t)(b * DIM + h * HD)) * KRNK;

  auto stageK = [&](int c, int bufi) {
#pragma unroll
    for (int i = 0; i < 2; ++i) {
      int sid = w * 128 + i * 64 + lane;
      int kr = sid >> 3, sl = sid & 7;
      glds16(kbase + (size_t)(c * 64 + kr) * DIM + ((sl ^ (kr & 7)) * 8),
             &sBuf[bufi][sid * 8]);
    }
  };
  auto stageV = [&](int c, int bufi) {
#pragma unroll
    for (int i = 0; i < 2; ++i) {
      int sid = w * 128 + i * 64 + lane;
      int hd = sid >> 3, sl = sid & 7;
      glds16(vbase + (size_t)hd * KRNK + c * 64 + ((sl ^ (hd & 7)) * 8),
             &sBuf[bufi][sid * 8]);
    }
  };

  int seqrow = qb * 64 + w * 16 + l15;
  const f16* qg = q + ((size_t)(b * SEQ + seqrow)) * DIM + h * HD;
  f16x8 aq[2];
  aq[0] = *(const f16x8*)(qg + hi * 8);
  aq[1] = *(const f16x8*)(qg + 32 + hi * 8);

  const f32x4 zero = {0.f, 0.f, 0.f, 0.f};
  f32x4 s[16];

  stageK(0, 0);
#pragma unroll
  for (int c = 0; c < 4; ++c) {
    __syncthreads();
    if (c < 3) stageK(c + 1, (c + 1) & 1);
    else       stageV(0, 0);
#pragma unroll
    for (int n = 0; n < 4; ++n) {
      int nn = c * 4 + n;
      s[nn] = zero;
      int krl = n * 16 + l15;
#pragma unroll
      for (int ks = 0; ks < 2; ++ks) {
        f16x8 bk = *(const f16x8*)&sBuf[c & 1][krl * 64 + (((ks * 4 + hi) ^ (krl & 7)) * 8)];
        s[nn] = __builtin_amdgcn_mfma_f32_16x16x32_f16(aq[ks], bk, s[nn], 0, 0, 0);
      }
    }
  }

  const float scale = 0.125f;
  float mx[4], sminv[4];
#pragma unroll
  for (int r = 0; r < 4; ++r) {
    float m0 = s[0][r];
#pragma unroll
    for (int n = 1; n < 16; ++n) m0 = fmaxf(m0, s[n][r]);
#pragma unroll
    for (int d = 1; d <= 8; d <<= 1) m0 = fmaxf(m0, __shfl_xor(m0, d));
    mx[r] = m0;
  }
  float sm[4] = {0.f, 0.f, 0.f, 0.f};
#pragma unroll
  for (int n = 0; n < 16; ++n)
#pragma unroll
    for (int r = 0; r < 4; ++r) {
      float p = __expf((s[n][r] - mx[r]) * scale);
      s[n][r] = p;
      sm[r] += p;
    }
#pragma unroll
  for (int r = 0; r < 4; ++r) {
    float t2 = sm[r];
#pragma unroll
    for (int d = 1; d <= 8; d <<= 1) t2 += __shfl_xor(t2, d);
    sminv[r] = 1.0f / t2;
  }

#pragma unroll
  for (int n = 0; n < 16; ++n)
#pragma unroll
    for (int r = 0; r < 4; ++r) {
      int qloc = w * 16 + hi * 4 + r;
      int kr = n * 16 + l15;
      int chunk = kr >> 3;
      sP[qloc * KRNK + ((chunk ^ (qloc & 7)) * 8) + (kr & 7)] = (f16)s[n][r];
    }

  f32x4 o[4];
#pragma unroll
  for (int n = 0; n < 4; ++n) o[n] = zero;
  int qloc = w * 16 + l15;
#pragma unroll
  for (int c = 0; c < 4; ++c) {
    __syncthreads();
    if (c < 3) stageV(c + 1, (c + 1) & 1);
#pragma unroll
    for (int sub = 0; sub < 2; ++sub) {
      int chunk = c * 8 + sub * 4 + hi;
      f16x8 pa = *(const f16x8*)&sP[qloc * KRNK + ((chunk ^ (qloc & 7)) * 8)];
#pragma unroll
      for (int n = 0; n < 4; ++n) {
        int hd = n * 16 + l15;
        f16x8 bv = *(const f16x8*)&sBuf[c & 1][hd * 64 + (((sub * 4 + hi) ^ (hd & 7)) * 8)];
        o[n] = __builtin_amdgcn_mfma_f32_16x16x32_f16(pa, bv, o[n], 0, 0, 0);
      }
    }
  }

  size_t obase = ((size_t)(b * SEQ + qb * 64)) * DIM + h * HD;
#pragma unroll
  for (int n = 0; n < 4; ++n)
#pragma unroll
    for (int r = 0; r < 4; ++r) {
      int qloc2 = w * 16 + hi * 4 + r;
      int hd = n * 16 + l15;
      oattn[obase + (size_t)qloc2 * DIM + hd] = (f16)(o[n][r] * sminv[r]);
    }
}

// ---------------- GO: out = oattn @ W_out + b_out (fp32 out) ----------------
__global__ __launch_bounds__(256) void k_go(const f16* __restrict__ oattn,
                                            const f16* __restrict__ WoT,
                                            const float* __restrict__ bias,
                                            float* __restrict__ out) {
  __shared__ __align__(16) f16 sA[128 * 64];
  __shared__ __align__(16) f16 sB[128 * 64];
  int bx = blockIdx.x;
  int mt = bx & 127, nt = bx >> 7;
  int bm = mt << 7, bn = nt << 7;
  f32x4 acc[4][4];
  mm_core<false, false, 128>(oattn, nullptr, DIM, WoT, nullptr, DIM, bm, bn, DIM,
                             sA, nullptr, sB, nullptr, acc);
  const int t = threadIdx.x, lane = t & 63, w = t >> 6;
  const int wr = w >> 1, wc = w & 1, l15 = lane & 15, hi = lane >> 4;
#pragma unroll
  for (int m = 0; m < 4; ++m)
#pragma unroll
    for (int n = 0; n < 4; ++n)
#pragma unroll
      for (int r = 0; r < 4; ++r) {
        int row = bm + wr * 64 + m * 16 + hi * 4 + r;
        int col = bn + wc * 64 + n * 16 + l15;
        out[(size_t)row * DIM + col] = acc[m][n][r] + bias[col];
      }
}

extern "C" void kernel_launch(void* const* d_in, const int* in_sizes, int n_in,
                              void* d_out, int out_size, void* d_ws, size_t ws_size,
                              hipStream_t stream) {
  const float* x    = (const float*)d_in[0];
  const float* Wqkv = (const float*)d_in[1];
  const float* E    = (const float*)d_in[2];
  const float* Wout = (const float*)d_in[3];
  const float* bout = (const float*)d_in[4];
  float* out = (float*)d_out;

  char* p = (char*)d_ws;
  f16* Wph = (f16*)p;  p += (size_t)2 * 3 * DIM * DIM;
  f16* Wpl = (f16*)p;  p += (size_t)2 * 3 * DIM * DIM;
  f16* WoT = (f16*)p;  p += (size_t)2 * DIM * DIM;
  f16* xh  = (f16*)p;  p += (size_t)2 * ROWS * DIM;
  f16* xth = (f16*)p;  p += (size_t)2 * DIM * ROWS;
  f16* xtl = (f16*)p;  p += (size_t)2 * DIM * ROWS;
  f16* Eth = (f16*)p;  p += (size_t)2 * KRNK * SEQ;
  f16* Etl = (f16*)p;  p += (size_t)2 * KRNK * SEQ;
  f16* XEh = (f16*)p;  p += (size_t)2 * NB * KRNK * DIM;
  f16* XEl = (f16*)p;  p += (size_t)2 * NB * KRNK * DIM;
  f16* kph = (f16*)p;  p += (size_t)2 * NB * KRNK * DIM;
  f16* vpt = (f16*)p;  p += (size_t)2 * NB * DIM * KRNK;
  float* XEp = (float*)p;  p += (size_t)4 * NSPLIT * NB * KRNK * DIM;  // 16.8 MB fp32
  size_t need = (size_t)(p - (char*)d_ws);
  if (ws_size < need) return;

  // aliases into xth/xtl (dead after k_xe2)
  f16* q     = xth;
  f16* oattn = xtl;

  k_prep_w<0><<<(DIM / 64) * (3 * DIM / 64), 256, 0, stream>>>(Wqkv, Wph, Wpl, DIM, 3 * DIM);
  k_prep_w<1><<<(DIM / 64) * (DIM / 64), 256, 0, stream>>>(Wout, WoT, nullptr, DIM, DIM);
  k_tsplit<true><<<(ROWS / 64) * (DIM / 64), 256, 0, stream>>>(x, xh, xth, xtl, ROWS, DIM);
  k_tsplit<false><<<(SEQ / 64) * (KRNK / 64), 256, 0, stream>>>(E, nullptr, Eth, Etl, SEQ, KRNK);
  k_xe2<<<512, 256, 0, stream>>>(Eth, Etl, xth, xtl, XEp);
  k_xered<<<(NB * KRNK * DIM / 4) / 256, 256, 0, stream>>>(XEp, XEh, XEl);
  k_gq<<<128 * 8, 256, 0, stream>>>(xh, Wph, q);
  k_t2<<<256, 256, 0, stream>>>(XEh, XEl, Wph, Wpl, kph, vpt);
  k_attn<<<64 * 64, 256, 0, stream>>>(q, kph, vpt, oattn);
  k_go<<<128 * 8, 256, 0, stream>>>(oattn, WoT, bout, out);
}

// Round 6
// 261.486 us; speedup vs baseline: 2.2141x; 1.0541x over previous
//
#include <hip/hip_runtime.h>
#include <hip/hip_bf16.h>

typedef _Float16 f16;
typedef __attribute__((ext_vector_type(4))) _Float16 f16x4;
typedef __attribute__((ext_vector_type(8))) _Float16 f16x8;
typedef __attribute__((ext_vector_type(4))) float f32x4;

#define DIM 1024
#define SEQ 4096
#define KRNK 256
#define NH 16
#define HD 64
#define NB 4
#define ROWS (NB*SEQ)   // 16384
#define NSPLIT 4

typedef const void __attribute__((address_space(1))) as1cv;
typedef void __attribute__((address_space(3))) as3v;

static __device__ __forceinline__ void glds16(const void* g, void* l) {
  __builtin_amdgcn_global_load_lds((as1cv*)g, (as3v*)l, 16, 0, 0);
}

// ---------------- W prep: transpose fp32 -> fp16 (MODE 0: scaled x256 hi/lo; 1: single) ----
template<int MODE>
__global__ __launch_bounds__(256) void k_prep_w(const float* __restrict__ in,
                                                f16* __restrict__ oh, f16* __restrict__ ol,
                                                int R, int C) {
  __shared__ float tile[64][65];
  int rtiles = R >> 6;
  int rt = blockIdx.x % rtiles, ct = blockIdx.x / rtiles;
  int r0 = rt << 6, c0 = ct << 6, t = threadIdx.x;
#pragma unroll
  for (int i = 0; i < 16; ++i) {
    int e = t + i * 256; int r = e >> 6, c = e & 63;
    tile[r][c] = in[(size_t)(r0 + r) * C + c0 + c];
  }
  __syncthreads();
#pragma unroll
  for (int i = 0; i < 16; ++i) {
    int e = t + i * 256; int c = e >> 6, r = e & 63;
    float v = tile[r][c];
    size_t idx = (size_t)(c0 + c) * R + r0 + r;
    if constexpr (MODE == 0) {
      v *= 256.0f;
      f16 h = (f16)v;
      oh[idx] = h;
      ol[idx] = (f16)(v - (float)h);
    } else {
      oh[idx] = (f16)v;
    }
  }
}

// ---------------- transpose prep: in[R][C] f32 -> oth[C][R] f16; opt oh[R][C] f16 ----
template<bool WH>
__global__ __launch_bounds__(256) void k_tsplit(const float* __restrict__ in,
                                                f16* __restrict__ oh,
                                                f16* __restrict__ oth,
                                                int R, int C) {
  __shared__ float tile[64][65];
  int rtiles = R >> 6;
  int rt = blockIdx.x % rtiles, ct = blockIdx.x / rtiles;
  int r0 = rt << 6, c0 = ct << 6, t = threadIdx.x;
  int cq = (t & 15) * 4, rr = t >> 4;
#pragma unroll
  for (int i = 0; i < 4; ++i) {
    int r = rr + i * 16;
    f32x4 v = *(const f32x4*)&in[(size_t)(r0 + r) * C + c0 + cq];
    tile[r][cq] = v[0]; tile[r][cq + 1] = v[1];
    tile[r][cq + 2] = v[2]; tile[r][cq + 3] = v[3];
    if constexpr (WH) {
      f16x4 h = {(f16)v[0], (f16)v[1], (f16)v[2], (f16)v[3]};
      *(f16x4*)&oh[(size_t)(r0 + r) * C + c0 + cq] = h;
    }
  }
  __syncthreads();
  int d4 = (t >> 4) * 4, sq = (t & 15) * 4;
#pragma unroll
  for (int j = 0; j < 4; ++j) {
    f16x4 h4;
#pragma unroll
    for (int k = 0; k < 4; ++k) h4[k] = (f16)tile[sq + k][d4 + j];
    *(f16x4*)&oth[(size_t)(c0 + d4 + j) * R + r0 + sq] = h4;
  }
}

// ---------------- generic MTxNT fp16 MFMA core, BK=64, 4 waves (2x2) ----------------
// C = (Ah[+Al]) * (Bh[+Bl])^T. A:[M][K] row-major, Bt:[N][K] row-major, all f16.
template<bool ASPL, bool BSPL, int MT, int NT>
static __device__ __forceinline__ void mm_core(
    const f16* __restrict__ Ah, const f16* __restrict__ Al, int lda,
    const f16* __restrict__ Bh, const f16* __restrict__ Bl, int ldb,
    int bm, int bn, int K,
    f16* sAh, f16* sAl, f16* sBh, f16* sBl,
    f32x4 (&acc)[MT / 32][NT / 32]) {
  constexpr int MREP = MT / 32, NREP = NT / 32;
  constexpr int AI = MT / 32, BI = NT / 32;   // staging iters (rows*8chunks/256thr)
  const int t = threadIdx.x;
  const int lane = t & 63, w = t >> 6;
  const int wr = w >> 1, wc = w & 1;
  const int l15 = lane & 15, hi = lane >> 4;
  const f32x4 zero = {0.f, 0.f, 0.f, 0.f};
#pragma unroll
  for (int m = 0; m < MREP; ++m)
#pragma unroll
    for (int n = 0; n < NREP; ++n) acc[m][n] = zero;

  for (int kk = 0; kk < K; kk += 64) {
#pragma unroll
    for (int i = 0; i < AI; ++i) {
      int c = t + i * 256;
      int row = c >> 3, cc = c & 7;
      size_t g = (size_t)(bm + row) * lda + kk + cc * 8;
      glds16(Ah + g, &sAh[c * 8]);
      if constexpr (ASPL) glds16(Al + g, &sAl[c * 8]);
    }
#pragma unroll
    for (int i = 0; i < BI; ++i) {
      int c = t + i * 256;
      int row = c >> 3, cc = c & 7;
      size_t g = (size_t)(bn + row) * ldb + kk + cc * 8;
      glds16(Bh + g, &sBh[c * 8]);
      if constexpr (BSPL) glds16(Bl + g, &sBl[c * 8]);
    }
    __syncthreads();

    f16x8 avh[MREP][2], avl[MREP][2], bvh[NREP][2], bvl[NREP][2];
#pragma unroll
    for (int m = 0; m < MREP; ++m)
#pragma unroll
      for (int ks = 0; ks < 2; ++ks) {
        int off = (wr * (MT / 2) + m * 16 + l15) * 64 + ks * 32 + hi * 8;
        avh[m][ks] = *(const f16x8*)&sAh[off];
        if constexpr (ASPL) avl[m][ks] = *(const f16x8*)&sAl[off];
      }
#pragma unroll
    for (int n = 0; n < NREP; ++n)
#pragma unroll
      for (int ks = 0; ks < 2; ++ks) {
        int off = (wc * (NT / 2) + n * 16 + l15) * 64 + ks * 32 + hi * 8;
        bvh[n][ks] = *(const f16x8*)&sBh[off];
        if constexpr (BSPL) bvl[n][ks] = *(const f16x8*)&sBl[off];
      }
#pragma unroll
    for (int m = 0; m < MREP; ++m)
#pragma unroll
      for (int n = 0; n < NREP; ++n)
#pragma unroll
        for (int ks = 0; ks < 2; ++ks) {
          if constexpr (ASPL && BSPL) {
            acc[m][n] = __builtin_amdgcn_mfma_f32_16x16x32_f16(avl[m][ks], bvh[n][ks], acc[m][n], 0, 0, 0);
            acc[m][n] = __builtin_amdgcn_mfma_f32_16x16x32_f16(avh[m][ks], bvl[n][ks], acc[m][n], 0, 0, 0);
          } else if constexpr (BSPL) {
            acc[m][n] = __builtin_amdgcn_mfma_f32_16x16x32_f16(avh[m][ks], bvl[n][ks], acc[m][n], 0, 0, 0);
          }
          acc[m][n] = __builtin_amdgcn_mfma_f32_16x16x32_f16(avh[m][ks], bvh[n][ks], acc[m][n], 0, 0, 0);
        }
    __syncthreads();
  }
}

// ---------------- XE partials: 1-term fp16 GEMM, split-K x4; fp32 partial out ----------------
__global__ __launch_bounds__(256) void k_xe2(const f16* __restrict__ Eth,
                                             const f16* __restrict__ xth,
                                             float* __restrict__ XEp) {
  __shared__ __align__(16) f16 sA[128 * 64];
  __shared__ __align__(16) f16 sB[64 * 64];
  int bx = blockIdx.x;                       // 512: nt(16) x mt(2) x b(4) x sp(4)
  int nt = bx & 15, mt = (bx >> 4) & 1, b = (bx >> 5) & 3, sp = bx >> 7;
  int bm = mt << 7, bn = nt << 6;
  int koff = sp * (SEQ / NSPLIT);
  f32x4 acc[4][2];
  mm_core<false, false, 128, 64>(Eth + koff, nullptr, SEQ,
                                 xth + (size_t)b * SEQ + koff, nullptr, ROWS,
                                 bm, bn, SEQ / NSPLIT, sA, nullptr, sB, nullptr, acc);
  const int t = threadIdx.x, lane = t & 63, w = t >> 6;
  const int wr = w >> 1, wc = w & 1, l15 = lane & 15, hi = lane >> 4;
#pragma unroll
  for (int m = 0; m < 4; ++m)
#pragma unroll
    for (int n = 0; n < 2; ++n)
#pragma unroll
      for (int r = 0; r < 4; ++r) {
        int kr = bm + wr * 64 + m * 16 + hi * 4 + r;
        int dd = bn + wc * 32 + n * 16 + l15;
        XEp[(((size_t)sp * NB + b) * KRNK + kr) * DIM + dd] = acc[m][n][r];
      }
}

// ---------------- XE reduce: sum 4 partials, h/l split f16 out ----------------
__global__ __launch_bounds__(256) void k_xered(const float* __restrict__ XEp,
                                               f16* __restrict__ XEh,
                                               f16* __restrict__ XEl) {
  size_t i = (size_t)blockIdx.x * 256 + threadIdx.x;   // f32x4 index
  const size_t sstride = (size_t)NB * KRNK * DIM / 4;
  const f32x4* p = (const f32x4*)XEp;
  f32x4 s = p[i];
#pragma unroll
  for (int sp = 1; sp < NSPLIT; ++sp) s += p[i + sp * sstride];
  f16x4 h4, l4;
#pragma unroll
  for (int j = 0; j < 4; ++j) {
    f16 h = (f16)s[j];
    h4[j] = h;
    l4[j] = (f16)(s[j] - (float)h);
  }
  *(f16x4*)&XEh[i * 4] = h4;
  *(f16x4*)&XEl[i * 4] = l4;
}

// ---------------- GQ: q = xh @ Wqh  (1 term), 64-row tiles, store fp16 ----------------
__global__ __launch_bounds__(256) void k_gq(const f16* __restrict__ xh,
                                            const f16* __restrict__ Wph,
                                            f16* __restrict__ q) {
  __shared__ __align__(16) f16 sA[64 * 64];
  __shared__ __align__(16) f16 sB[128 * 64];
  int bx = blockIdx.x;                 // 2048: mt(256) x nt(8)
  int mt = bx & 255, nt = bx >> 8;
  int bm = mt << 6, bn = nt << 7;
  f32x4 acc[2][4];
  mm_core<false, false, 64, 128>(xh, nullptr, DIM, Wph, nullptr, DIM, bm, bn, DIM,
                                 sA, nullptr, sB, nullptr, acc);
  const int t = threadIdx.x, lane = t & 63, w = t >> 6;
  const int wr = w >> 1, wc = w & 1, l15 = lane & 15, hi = lane >> 4;
#pragma unroll
  for (int m = 0; m < 2; ++m)
#pragma unroll
    for (int n = 0; n < 4; ++n)
#pragma unroll
      for (int r = 0; r < 4; ++r) {
        int row = bm + wr * 32 + m * 16 + hi * 4 + r;
        int col = bn + wc * 64 + n * 16 + l15;
        q[(size_t)row * DIM + col] = (f16)(acc[m][n][r] * (1.0f / 256.0f));
      }
}

// ---------------- T2: kp/vp = (XEh+XEl) @ (W{k,v}h+l)  (3 terms), 64-wide tiles ----
__global__ __launch_bounds__(256) void k_t2(const f16* __restrict__ XEh,
                                            const f16* __restrict__ XEl,
                                            const f16* __restrict__ Wph,
                                            const f16* __restrict__ Wpl,
                                            f16* __restrict__ kph,
                                            f16* __restrict__ vpt) {
  __shared__ __align__(16) f16 sAh[128 * 64], sAl[128 * 64];
  __shared__ __align__(16) f16 sBh[64 * 64], sBl[64 * 64];
  int bx = blockIdx.x;                       // 256: nt(16) x mt(2) x b(4) x kv(2)
  int nt = bx & 15, mt = (bx >> 4) & 1, b = (bx >> 5) & 3, kv = bx >> 7;
  size_t abase = (size_t)b * KRNK * DIM;
  size_t wbase = (size_t)(DIM + kv * DIM) * DIM;
  f32x4 acc[4][2];
  mm_core<true, true, 128, 64>(XEh + abase, XEl + abase, DIM, Wph + wbase, Wpl + wbase, DIM,
                               mt << 7, nt << 6, DIM, sAh, sAl, sBh, sBl, acc);
  const int t = threadIdx.x, lane = t & 63, w = t >> 6;
  const int wr = w >> 1, wc = w & 1, l15 = lane & 15, hi = lane >> 4;
#pragma unroll
  for (int m = 0; m < 4; ++m)
#pragma unroll
    for (int n = 0; n < 2; ++n)
#pragma unroll
      for (int r = 0; r < 4; ++r) {
        int row = (mt << 7) + wr * 64 + m * 16 + hi * 4 + r;   // kr
        int col = (nt << 6) + wc * 32 + n * 16 + l15;          // dd
        float s = acc[m][n][r] * (1.0f / 256.0f);
        if (!kv) kph[((size_t)(b * KRNK + row)) * DIM + col] = (f16)s;
        else     vpt[((size_t)(b * DIM + col)) * KRNK + row] = (f16)s;
      }
}

// ---------------- fused attention: async-staged scores -> softmax -> PV ----------------
__global__ __launch_bounds__(256) void k_attn(const f16* __restrict__ q,
                                              const f16* __restrict__ kph,
                                              const f16* __restrict__ vpt,
                                              f16* __restrict__ oattn) {
  __shared__ __align__(16) f16 sBuf[2][64 * 64];   // 2 x 8 KB staging
  __shared__ __align__(16) f16 sP[64 * KRNK];      // 32 KB
  int bx0 = blockIdx.x;
  int swz = (bx0 & 7) * 512 + (bx0 >> 3);          // XCD-contiguous (4096 % 8 == 0)
  int qb = swz & 63;
  int bh = swz >> 6;
  int b = bh >> 4, h = bh & 15;
  int t = threadIdx.x;
  int lane = t & 63, w = t >> 6;
  int l15 = lane & 15, hi = lane >> 4;

  const f16* kbase = kph + ((size_t)(b * KRNK)) * DIM + h * HD;
  const f16* vbase = vpt + ((size_t)(b * DIM + h * HD)) * KRNK;

  auto stageK = [&](int c, int bufi) {
#pragma unroll
    for (int i = 0; i < 2; ++i) {
      int sid = w * 128 + i * 64 + lane;
      int kr = sid >> 3, sl = sid & 7;
      glds16(kbase + (size_t)(c * 64 + kr) * DIM + ((sl ^ (kr & 7)) * 8),
             &sBuf[bufi][sid * 8]);
    }
  };
  auto stageV = [&](int c, int bufi) {
#pragma unroll
    for (int i = 0; i < 2; ++i) {
      int sid = w * 128 + i * 64 + lane;
      int hd = sid >> 3, sl = sid & 7;
      glds16(vbase + (size_t)hd * KRNK + c * 64 + ((sl ^ (hd & 7)) * 8),
             &sBuf[bufi][sid * 8]);
    }
  };

  int seqrow = qb * 64 + w * 16 + l15;
  const f16* qg = q + ((size_t)(b * SEQ + seqrow)) * DIM + h * HD;
  f16x8 aq[2];
  aq[0] = *(const f16x8*)(qg + hi * 8);
  aq[1] = *(const f16x8*)(qg + 32 + hi * 8);

  const f32x4 zero = {0.f, 0.f, 0.f, 0.f};
  f32x4 s[16];

  stageK(0, 0);
#pragma unroll
  for (int c = 0; c < 4; ++c) {
    __syncthreads();
    if (c < 3) stageK(c + 1, (c + 1) & 1);
    else       stageV(0, 0);
#pragma unroll
    for (int n = 0; n < 4; ++n) {
      int nn = c * 4 + n;
      s[nn] = zero;
      int krl = n * 16 + l15;
#pragma unroll
      for (int ks = 0; ks < 2; ++ks) {
        f16x8 bk = *(const f16x8*)&sBuf[c & 1][krl * 64 + (((ks * 4 + hi) ^ (krl & 7)) * 8)];
        s[nn] = __builtin_amdgcn_mfma_f32_16x16x32_f16(aq[ks], bk, s[nn], 0, 0, 0);
      }
    }
  }

  const float scale = 0.125f;
  float mx[4], sminv[4];
#pragma unroll
  for (int r = 0; r < 4; ++r) {
    float m0 = s[0][r];
#pragma unroll
    for (int n = 1; n < 16; ++n) m0 = fmaxf(m0, s[n][r]);
#pragma unroll
    for (int d = 1; d <= 8; d <<= 1) m0 = fmaxf(m0, __shfl_xor(m0, d));
    mx[r] = m0;
  }
  float sm[4] = {0.f, 0.f, 0.f, 0.f};
#pragma unroll
  for (int n = 0; n < 16; ++n)
#pragma unroll
    for (int r = 0; r < 4; ++r) {
      float p = __expf((s[n][r] - mx[r]) * scale);
      s[n][r] = p;
      sm[r] += p;
    }
#pragma unroll
  for (int r = 0; r < 4; ++r) {
    float t2 = sm[r];
#pragma unroll
    for (int d = 1; d <= 8; d <<= 1) t2 += __shfl_xor(t2, d);
    sminv[r] = 1.0f / t2;
  }

#pragma unroll
  for (int n = 0; n < 16; ++n)
#pragma unroll
    for (int r = 0; r < 4; ++r) {
      int qloc = w * 16 + hi * 4 + r;
      int kr = n * 16 + l15;
      int chunk = kr >> 3;
      sP[qloc * KRNK + ((chunk ^ (qloc & 7)) * 8) + (kr & 7)] = (f16)s[n][r];
    }

  f32x4 o[4];
#pragma unroll
  for (int n = 0; n < 4; ++n) o[n] = zero;
  int qloc = w * 16 + l15;
#pragma unroll
  for (int c = 0; c < 4; ++c) {
    __syncthreads();
    if (c < 3) stageV(c + 1, (c + 1) & 1);
#pragma unroll
    for (int sub = 0; sub < 2; ++sub) {
      int chunk = c * 8 + sub * 4 + hi;
      f16x8 pa = *(const f16x8*)&sP[qloc * KRNK + ((chunk ^ (qloc & 7)) * 8)];
#pragma unroll
      for (int n = 0; n < 4; ++n) {
        int hd = n * 16 + l15;
        f16x8 bv = *(const f16x8*)&sBuf[c & 1][hd * 64 + (((sub * 4 + hi) ^ (hd & 7)) * 8)];
        o[n] = __builtin_amdgcn_mfma_f32_16x16x32_f16(pa, bv, o[n], 0, 0, 0);
      }
    }
  }

  size_t obase = ((size_t)(b * SEQ + qb * 64)) * DIM + h * HD;
#pragma unroll
  for (int n = 0; n < 4; ++n)
#pragma unroll
    for (int r = 0; r < 4; ++r) {
      int qloc2 = w * 16 + hi * 4 + r;
      int hd = n * 16 + l15;
      oattn[obase + (size_t)qloc2 * DIM + hd] = (f16)(o[n][r] * sminv[r]);
    }
}

// ---------------- GO: out = oattn @ W_out + b_out, 64-row tiles (fp32 out) ----------------
__global__ __launch_bounds__(256) void k_go(const f16* __restrict__ oattn,
                                            const f16* __restrict__ WoT,
                                            const float* __restrict__ bias,
                                            float* __restrict__ out) {
  __shared__ __align__(16) f16 sA[64 * 64];
  __shared__ __align__(16) f16 sB[128 * 64];
  int bx = blockIdx.x;                 // 2048: mt(256) x nt(8)
  int mt = bx & 255, nt = bx >> 8;
  int bm = mt << 6, bn = nt << 7;
  f32x4 acc[2][4];
  mm_core<false, false, 64, 128>(oattn, nullptr, DIM, WoT, nullptr, DIM, bm, bn, DIM,
                                 sA, nullptr, sB, nullptr, acc);
  const int t = threadIdx.x, lane = t & 63, w = t >> 6;
  const int wr = w >> 1, wc = w & 1, l15 = lane & 15, hi = lane >> 4;
#pragma unroll
  for (int m = 0; m < 2; ++m)
#pragma unroll
    for (int n = 0; n < 4; ++n)
#pragma unroll
      for (int r = 0; r < 4; ++r) {
        int row = bm + wr * 32 + m * 16 + hi * 4 + r;
        int col = bn + wc * 64 + n * 16 + l15;
        out[(size_t)row * DIM + col] = acc[m][n][r] + bias[col];
      }
}

extern "C" void kernel_launch(void* const* d_in, const int* in_sizes, int n_in,
                              void* d_out, int out_size, void* d_ws, size_t ws_size,
                              hipStream_t stream) {
  const float* x    = (const float*)d_in[0];
  const float* Wqkv = (const float*)d_in[1];
  const float* E    = (const float*)d_in[2];
  const float* Wout = (const float*)d_in[3];
  const float* bout = (const float*)d_in[4];
  float* out = (float*)d_out;

  char* p = (char*)d_ws;
  f16* Wph = (f16*)p;  p += (size_t)2 * 3 * DIM * DIM;   //  6.29 MB
  f16* Wpl = (f16*)p;  p += (size_t)2 * 3 * DIM * DIM;
  f16* WoT = (f16*)p;  p += (size_t)2 * DIM * DIM;
  f16* xh  = (f16*)p;  p += (size_t)2 * ROWS * DIM;      // 33.55 MB
  f16* xth = (f16*)p;  p += (size_t)2 * DIM * ROWS;      // 33.55 MB
  f16* Eth = (f16*)p;  p += (size_t)2 * KRNK * SEQ;
  f16* XEh = (f16*)p;  p += (size_t)2 * NB * KRNK * DIM;
  f16* XEl = (f16*)p;  p += (size_t)2 * NB * KRNK * DIM;
  f16* kph = (f16*)p;  p += (size_t)2 * NB * KRNK * DIM;
  f16* vpt = (f16*)p;  p += (size_t)2 * NB * DIM * KRNK;
  f16* oattn = (f16*)p; p += (size_t)2 * ROWS * DIM;     // 33.55 MB
  float* XEp = (float*)p;  p += (size_t)4 * NSPLIT * NB * KRNK * DIM;  // 16.8 MB
  size_t need = (size_t)(p - (char*)d_ws);
  if (ws_size < need) return;

  f16* q = xth;   // alias: xth dead after k_xe2; k_gq runs after it

  k_prep_w<0><<<(DIM / 64) * (3 * DIM / 64), 256, 0, stream>>>(Wqkv, Wph, Wpl, DIM, 3 * DIM);
  k_prep_w<1><<<(DIM / 64) * (DIM / 64), 256, 0, stream>>>(Wout, WoT, nullptr, DIM, DIM);
  k_tsplit<true><<<(ROWS / 64) * (DIM / 64), 256, 0, stream>>>(x, xh, xth, ROWS, DIM);
  k_tsplit<false><<<(SEQ / 64) * (KRNK / 64), 256, 0, stream>>>(E, nullptr, Eth, SEQ, KRNK);
  k_xe2<<<512, 256, 0, stream>>>(Eth, xth, XEp);
  k_xered<<<(NB * KRNK * DIM / 4) / 256, 256, 0, stream>>>(XEp, XEh, XEl);
  k_gq<<<2048, 256, 0, stream>>>(xh, Wph, q);
  k_t2<<<256, 256, 0, stream>>>(XEh, XEl, Wph, Wpl, kph, vpt);
  k_attn<<<64 * 64, 256, 0, stream>>>(q, kph, vpt, oattn);
  k_go<<<2048, 256, 0, stream>>>(oattn, WoT, bout, out);
}